// Round 1
// baseline (271.103 us; speedup 1.0000x reference)
//
#include <hip/hip_runtime.h>
#include <stdint.h>
#include <stddef.h>

// ---------- types ----------
typedef __attribute__((ext_vector_type(8))) short s16x8;
typedef __attribute__((ext_vector_type(4))) short s16x4;
typedef __attribute__((ext_vector_type(4))) float f32x4;

#define MFMA(a,b,c) __builtin_amdgcn_mfma_f32_16x16x32_bf16((a),(b),(c),0,0,0)

static __device__ __forceinline__ unsigned short f2b(float f){
  unsigned int b = __float_as_uint(f);
  b = (b + 0x7FFFu + ((b>>16)&1u)) >> 16;     // RNE
  return (unsigned short)b;
}
static __device__ __forceinline__ float b2f(unsigned short u){
  return __uint_as_float(((unsigned int)u)<<16);
}

// B=2, T1=1024, T2=512, H=16, DH=64, DM=1024, SCALE=0.125

// ---------- mask dtype detector ----------
// int32 0/1: bytes at off%4!=0 are all zero. uint8 bool: nonzero at %4==1.
// f32 1.0f: nonzero only at %4==2,3 (0x80,0x3F). flag: 0=int32,1=uint8,2=f32
__global__ void k_detect(const unsigned char* __restrict__ m, int* __restrict__ flag){
  __shared__ int c1, c23;
  if(threadIdx.x==0){ c1=0; c23=0; }
  __syncthreads();
  int l1=0,l23=0;
  for(int i=threadIdx.x;i<65536;i+=256){
    if(m[i]){ int r=i&3; if(r==1) l1++; else if(r>=2) l23++; }
  }
  atomicAdd(&c1,l1); atomicAdd(&c23,l23);
  __syncthreads();
  if(threadIdx.x==0) flag[0] = c1 ? 1 : (c23 ? 2 : 0);
}

static __device__ __forceinline__ bool mload(const void* m, int flag, size_t idx){
  if(flag==0) return ((const int*)m)[idx]!=0;
  if(flag==1) return ((const unsigned char*)m)[idx]!=0;
  return ((const float*)m)[idx]!=0.f;
}

// ---------- LayerNorm(Q) -> bf16 ----------
__global__ __launch_bounds__(256) void k_ln(const float* __restrict__ Q,
    const float* __restrict__ g, const float* __restrict__ be,
    unsigned short* __restrict__ Qn){
  int row = blockIdx.x;                      // 2048
  const float4* xp = (const float4*)(Q + (size_t)row*1024);
  float4 v = xp[threadIdx.x];
  float s  = v.x+v.y+v.z+v.w;
  float s2 = v.x*v.x+v.y*v.y+v.z*v.z+v.w*v.w;
  #pragma unroll
  for(int o=1;o<64;o<<=1){ s += __shfl_xor(s,o); s2 += __shfl_xor(s2,o); }
  __shared__ float red[8];
  int w = threadIdx.x>>6, l = threadIdx.x&63;
  if(l==0){ red[w]=s; red[4+w]=s2; }
  __syncthreads();
  s  = red[0]+red[1]+red[2]+red[3];
  s2 = red[4]+red[5]+red[6]+red[7];
  float mu = s*(1.f/1024.f);
  float var = s2*(1.f/1024.f) - mu*mu;
  float rs = rsqrtf(var + 1e-5f);
  float4 gv = ((const float4*)g)[threadIdx.x];
  float4 bv = ((const float4*)be)[threadIdx.x];
  ushort4 o4;
  o4.x = f2b((v.x-mu)*rs*gv.x + bv.x);
  o4.y = f2b((v.y-mu)*rs*gv.y + bv.y);
  o4.z = f2b((v.z-mu)*rs*gv.z + bv.z);
  o4.w = f2b((v.w-mu)*rs*gv.w + bv.w);
  ((ushort4*)(Qn + (size_t)row*1024))[threadIdx.x] = o4;
}

// ---------- transpose+cast the 4 weight matrices: D[n][k] = bf16(W[k][n]) ----------
__global__ __launch_bounds__(256) void k_transpose(
    const float* __restrict__ W0, const float* __restrict__ W1,
    const float* __restrict__ W2, const float* __restrict__ W3,
    unsigned short* __restrict__ D0, unsigned short* __restrict__ D1,
    unsigned short* __restrict__ D2, unsigned short* __restrict__ D3){
  __shared__ float tile[64][65];
  const float* S = blockIdx.z==0?W0: blockIdx.z==1?W1: blockIdx.z==2?W2:W3;
  unsigned short* D = blockIdx.z==0?D0: blockIdx.z==1?D1: blockIdx.z==2?D2:D3;
  int k0 = blockIdx.x*64, n0 = blockIdx.y*64;
  int tr = threadIdx.x>>6, tc = threadIdx.x&63;
  #pragma unroll
  for(int it=0;it<16;it++){ int r = it*4+tr; tile[r][tc] = S[(size_t)(k0+r)*1024 + n0+tc]; }
  __syncthreads();
  #pragma unroll
  for(int it=0;it<16;it++){ int r = it*4+tr; D[(size_t)(n0+r)*1024 + k0+tc] = f2b(tile[tc][r]); }
}

// ---------- gather valid_frames rows of K,V and cast to bf16 ----------
__global__ __launch_bounds__(256) void k_gather(const float* __restrict__ K,
    const float* __restrict__ V, const int* __restrict__ vf,
    unsigned short* __restrict__ Kg, unsigned short* __restrict__ Vg){
  int row = blockIdx.x;             // 0..2047
  int isV = row>>10, r = row&1023;
  int b = r>>9, jj = r&511;
  const float* src = (isV? V : K) + ((size_t)(b*1024 + vf[jj]))*1024;
  unsigned short* dst = (isV? Vg : Kg) + (size_t)r*1024;
  float4 v = ((const float4*)src)[threadIdx.x];
  ushort4 o; o.x=f2b(v.x); o.y=f2b(v.y); o.z=f2b(v.z); o.w=f2b(v.w);
  ((ushort4*)dst)[threadIdx.x] = o;
}

__global__ void k_castL(const float* __restrict__ L, unsigned short* __restrict__ Lb){
  int i = blockIdx.x*256 + threadIdx.x;
  if(i < 2047*64) Lb[i] = f2b(L[i]);
}

// ---------- generic bf16 GEMM: C = A(MxK) @ Bt(NxK)^T, K=1024, tile 128x128 ----------
// MODE 0: q proj  -> qb[(b*16+h)*1024+i][64] bf16   (A rows = b*1024+i, cols = h*64+d)
// MODE 1: k proj  -> kb[(b*16+h)*512+jj][64] bf16   (A rows = b*512+jj)
// MODE 2: v projT -> vT[(b*16+h)*64+d][512] bf16    (A rows = h*64+d, cols = b*512+jj)
// MODE 3: out     -> f32 out[m][n] = acc + bo[n] + ctxf[m][n]
template<int MODE>
__global__ __launch_bounds__(256) void k_gemm(
    const short* __restrict__ A, const short* __restrict__ Bt,
    void* __restrict__ out, const float* __restrict__ bo,
    const float* __restrict__ ctxf){
  __shared__ __align__(16) short Ab[128*32];
  __shared__ __align__(16) short Bb[128*32];
  const int t = threadIdx.x;
  const int w = t>>6, l = t&63;
  const int wr = w>>1, wc = w&1;
  const int fl15 = l&15, fl4 = l>>4;
  const size_t m0 = (size_t)blockIdx.x*128, n0 = (size_t)blockIdx.y*128;
  const int srow = t>>2, scb = t&3;
  const int sg = scb ^ ((srow>>1)&3);        // swizzled source granule
  const short* Ap = A + (m0+srow)*1024 + 8*sg;
  const short* Bp = Bt + (n0+srow)*1024 + 8*sg;

  f32x4 acc[4][4];
  const f32x4 zero = {0.f,0.f,0.f,0.f};
  #pragma unroll
  for(int m=0;m<4;m++)
    #pragma unroll
    for(int n=0;n<4;n++) acc[m][n] = zero;

  for(int k0=0;k0<1024;k0+=32){
    s16x8 a0 = *(const s16x8*)(Ap + k0);
    s16x8 a1 = *(const s16x8*)(Ap + 64*1024 + k0);
    s16x8 b0 = *(const s16x8*)(Bp + k0);
    s16x8 b1 = *(const s16x8*)(Bp + 64*1024 + k0);
    __syncthreads();
    *(s16x8*)(Ab + srow*32 + scb*8)      = a0;
    *(s16x8*)(Ab + (64+srow)*32 + scb*8) = a1;
    *(s16x8*)(Bb + srow*32 + scb*8)      = b0;
    *(s16x8*)(Bb + (64+srow)*32 + scb*8) = b1;
    __syncthreads();
    s16x8 af[4], bff[4];
    #pragma unroll
    for(int m=0;m<4;m++){
      int row = wr*64 + m*16 + fl15;
      int gg = fl4 ^ ((row>>1)&3);
      af[m] = *(const s16x8*)(Ab + row*32 + gg*8);
    }
    #pragma unroll
    for(int n=0;n<4;n++){
      int row = wc*64 + n*16 + fl15;
      int gg = fl4 ^ ((row>>1)&3);
      bff[n] = *(const s16x8*)(Bb + row*32 + gg*8);
    }
    #pragma unroll
    for(int m=0;m<4;m++)
      #pragma unroll
      for(int n=0;n<4;n++)
        acc[m][n] = MFMA(af[m], bff[n], acc[m][n]);
  }

  #pragma unroll
  for(int m=0;m<4;m++){
    #pragma unroll
    for(int n=0;n<4;n++){
      int mgb = (int)m0 + wr*64 + m*16 + 4*fl4;
      int ng  = (int)n0 + wc*64 + n*16 + fl15;
      #pragma unroll
      for(int p=0;p<4;p++){
        int mg = mgb + p;
        float v = acc[m][n][p];
        if(MODE==0){ int b=mg>>10, i=mg&1023, h=ng>>6, d=ng&63;
          ((unsigned short*)out)[((size_t)((b*16+h)*1024+i))*64 + d] = f2b(v); }
        else if(MODE==1){ int b=mg>>9, jj=mg&511, h=ng>>6, d=ng&63;
          ((unsigned short*)out)[((size_t)((b*16+h)*512+jj))*64 + d] = f2b(v); }
        else if(MODE==2){ int h=mg>>6, d=mg&63, b=ng>>9, jj=ng&511;
          ((unsigned short*)out)[((size_t)((b*16+h)*64+d))*512 + jj] = f2b(v); }
        else { size_t idx = (size_t)mg*1024 + ng;
          ((float*)out)[idx] = v + bo[ng] + ctxf[idx]; }
      }
    }
  }
}

// ---------- rel: RELG[bh][qg][t][lane][p] = bf16( q_i . L[1023+vf[jj]-i] ) ----------
// rel[i,jj] = (q @ L^T)[i, 1023+vf[jj]-i]; per 16-row wave compute the needed
// x-window of G = q16 @ L^T (width<=1039) in two 528-wide LDS chunks, then gather.
#define GS 536
__global__ __launch_bounds__(128) void k_rel(const short* __restrict__ qb,
    const short* __restrict__ lbf, const int* __restrict__ vf,
    unsigned short* __restrict__ relg){
  __shared__ __align__(16) short G[2][16*GS];
  __shared__ int vfs[512];
  const int t=threadIdx.x, w=t>>6, l=t&63, fl15=l&15, fl4=l>>4;
  const int bh  = blockIdx.x >> 5;
  const int qt2 = blockIdx.x & 31;
  const int qw  = qt2*32 + w*16;
  for(int i=t;i<512;i+=128) vfs[i]=vf[i];
  __syncthreads();
  const int vf0 = vfs[0];
  const int x0 = 1008 + vf0 - qw;            // >= 0
  const short* qp = qb + ((size_t)(bh*1024 + qw + fl15))*64 + 8*fl4;
  s16x8 qa0 = *(const s16x8*)qp;
  s16x8 qa1 = *(const s16x8*)(qp+32);
  short* Gw = &G[w][0];
  const f32x4 zero = {0.f,0.f,0.f,0.f};
  for(int c=0;c<2;c++){
    int xc = x0 + c*528;
    #pragma unroll 4
    for(int tt=0;tt<33;tt++){
      int xr = xc + tt*16 + fl15; if(xr>2046) xr = 2046;
      const short* lp = lbf + (size_t)xr*64 + 8*fl4;
      s16x8 b0v = *(const s16x8*)lp;
      s16x8 b1v = *(const s16x8*)(lp+32);
      f32x4 a = zero;
      a = MFMA(qa0,b0v,a); a = MFMA(qa1,b1v,a);
      #pragma unroll
      for(int p=0;p<4;p++) Gw[(4*fl4+p)*GS + tt*16 + fl15] = (short)f2b(a[p]);
    }
    __syncthreads();
    #pragma unroll 4
    for(int tt=0;tt<32;tt++){
      int jj = tt*16 + fl15;
      int xv = 1023 + vfs[jj] - qw;          // x for r=0
      #pragma unroll
      for(int p=0;p<4;p++){
        int r = 4*fl4 + p;
        int xloc = xv - r - xc;
        if(xloc>=0 && xloc<528){
          relg[((size_t)((bh*64 + qt2*2 + w)*32 + tt))*256 + l*4 + p]
            = (unsigned short)Gw[r*GS + xloc];
        }
      }
    }
    __syncthreads();
  }
}

// ---------- fused attention: S=(qk^T + rel)*SCALE, mask, softmax, ctx = P@v ----------
__global__ __launch_bounds__(256) void k_attn(const short* __restrict__ qb,
    const short* __restrict__ kb, const short* __restrict__ vt,
    const short* __restrict__ relg, const void* __restrict__ mask,
    const int* __restrict__ flagp,
    unsigned short* __restrict__ ctxb, float* __restrict__ ctxf){
  __shared__ __align__(16) short P[4][16*512];   // 64 KiB, per-wave 16x512 bf16 (XOR-swizzled)
  const int t=threadIdx.x, w=t>>6, l=t&63, fl15=l&15, fl4=l>>4;
  const int bh = blockIdx.y;       // 0..31
  const int qt = blockIdx.x;       // 0..15
  const int qw = qt*64 + w*16;
  const int qg = qt*4 + w;
  const int flag = *flagp;
  short* Pw = &P[w][0];
  unsigned int* mw = (unsigned int*)Pw;          // mask bits live in row0 area until S done

  // --- pack mask bits via ballot: mw[r*16 + (jj>>5)], bit jj&31 ---
  for(int r=0;r<16;r++){
    size_t mbase = ((size_t)(bh*1024 + qw + r))*512;
    #pragma unroll
    for(int c=0;c<8;c++){
      bool mk = mload(mask, flag, mbase + c*64 + l);
      unsigned long long bal = __ballot(mk);
      if(l==0){ mw[r*16 + c*2] = (unsigned int)bal; mw[r*16 + c*2 + 1] = (unsigned int)(bal>>32); }
    }
  }
  __syncthreads();
  unsigned int mbits[4];
  #pragma unroll
  for(int p=0;p<4;p++){
    int r = 4*fl4+p;
    unsigned int bs = 0;
    #pragma unroll
    for(int u=0;u<16;u++){
      unsigned int wv = mw[r*16+u];
      bs |= ((wv>>fl15)&1u) << (2*u);
      bs |= ((wv>>(16+fl15))&1u) << (2*u+1);
    }
    mbits[p] = bs;
  }

  // --- q fragments (in regs for all 32 key tiles) ---
  const short* qp = qb + ((size_t)(bh*1024 + qw + fl15))*64 + 8*fl4;
  s16x8 qa0 = *(const s16x8*)qp;
  s16x8 qa1 = *(const s16x8*)(qp+32);

  const f32x4 zero = {0.f,0.f,0.f,0.f};
  f32x4 S[32];
  #pragma unroll
  for(int tt=0;tt<32;tt++){
    const short* kp = kb + ((size_t)(bh*512 + tt*16 + fl15))*64 + 8*fl4;
    s16x8 k0v = *(const s16x8*)kp;
    s16x8 k1v = *(const s16x8*)(kp+32);
    f32x4 a = zero;
    a = MFMA(qa0,k0v,a); a = MFMA(qa1,k1v,a);
    s16x4 rl = *(const s16x4*)(relg + ((size_t)((bh*64+qg)*32+tt))*256 + l*4);
    #pragma unroll
    for(int p=0;p<4;p++){
      float sv = (a[p] + b2f((unsigned short)rl[p])) * 0.125f;
      bool mskb = (mbits[p]>>tt)&1u;
      a[p] = mskb ? -3.402823466e38f : sv;
    }
    S[tt] = a;
  }

  // --- softmax over 512 keys (rows split: 16 lanes x 32 tiles) ---
  float mx[4] = {-3.402823466e38f,-3.402823466e38f,-3.402823466e38f,-3.402823466e38f};
  #pragma unroll
  for(int tt=0;tt<32;tt++)
    #pragma unroll
    for(int p=0;p<4;p++) mx[p] = fmaxf(mx[p], S[tt][p]);
  #pragma unroll
  for(int o=1;o<16;o<<=1)
    #pragma unroll
    for(int p=0;p<4;p++) mx[p] = fmaxf(mx[p], __shfl_xor(mx[p],o));
  float sm[4] = {0.f,0.f,0.f,0.f};
  #pragma unroll
  for(int tt=0;tt<32;tt++){
    #pragma unroll
    for(int p=0;p<4;p++){
      float e = __expf(S[tt][p]-mx[p]);
      sm[p] += e;
      int r = 4*fl4+p, jj = tt*16+fl15;
      int gp = (jj>>3) ^ (r&7);
      Pw[r*512 + gp*8 + (jj&7)] = (short)f2b(e);   // unnormalized P
    }
  }
  #pragma unroll
  for(int o=1;o<16;o<<=1)
    #pragma unroll
    for(int p=0;p<4;p++) sm[p] += __shfl_xor(sm[p],o);
  float inv[4];
  #pragma unroll
  for(int p=0;p<4;p++) inv[p] = 1.f/sm[p];
  __syncthreads();

  // --- ctx = P @ v, v read as vT[d][key] ---
  const int b = bh>>4, h = bh&15;
  const int irow0 = qw + 4*fl4;
  #pragma unroll
  for(int dt=0;dt<4;dt++){
    f32x4 pa = zero;
    const short* vp = vt + ((size_t)(bh*64 + dt*16 + fl15))*512 + 8*fl4;
    #pragma unroll
    for(int s=0;s<16;s++){
      int gp = (4*s + fl4) ^ (fl15&7);
      s16x8 af = *(const s16x8*)(Pw + fl15*512 + gp*8);
      s16x8 bf_ = *(const s16x8*)(vp + 32*s);
      pa = MFMA(af, bf_, pa);
    }
    #pragma unroll
    for(int p=0;p<4;p++){
      float val = pa[p] * inv[p];
      size_t idx = ((size_t)(b*1024 + irow0 + p))*1024 + h*64 + dt*16 + fl15;
      ctxb[idx] = f2b(val);
      ctxf[idx] = val;
    }
  }
}

// ---------- launch ----------
extern "C" void kernel_launch(void* const* d_in, const int* in_sizes, int n_in,
                              void* d_out, int out_size, void* d_ws, size_t ws_size,
                              hipStream_t stream){
  (void)in_sizes; (void)n_in; (void)out_size; (void)ws_size;
  const float* Q  = (const float*)d_in[0];
  const float* K  = (const float*)d_in[1];
  const float* V  = (const float*)d_in[2];
  const float* Lt = (const float*)d_in[3];
  const int*   vf = (const int*)d_in[4];
  const void*  mk = d_in[5];
  const float* Wq = (const float*)d_in[6];
  const float* Wk = (const float*)d_in[7];
  const float* Wv = (const float*)d_in[8];
  const float* Wo = (const float*)d_in[9];
  const float* bo = (const float*)d_in[10];
  const float* lg = (const float*)d_in[11];
  const float* lb = (const float*)d_in[12];

  char* base = (char*)d_ws;
  size_t off = 0;
  auto alloc = [&](size_t bytes)->char*{
    char* p = base + off; off += (bytes + 255) & ~(size_t)255; return p; };
  int* flag           = (int*)alloc(256);
  unsigned short* QN  = (unsigned short*)alloc(2048ull*1024*2);
  unsigned short* KG  = (unsigned short*)alloc(1024ull*1024*2);
  unsigned short* VG  = (unsigned short*)alloc(1024ull*1024*2);
  unsigned short* WQT = (unsigned short*)alloc(1024ull*1024*2);
  unsigned short* WKT = (unsigned short*)alloc(1024ull*1024*2);
  unsigned short* WVT = (unsigned short*)alloc(1024ull*1024*2);
  unsigned short* WOT = (unsigned short*)alloc(1024ull*1024*2);
  unsigned short* LB  = (unsigned short*)alloc(2047ull*64*2);
  unsigned short* QB  = (unsigned short*)alloc(32ull*1024*64*2);
  unsigned short* KB  = (unsigned short*)alloc(32ull*512*64*2);
  unsigned short* VT  = (unsigned short*)alloc(32ull*64*512*2);
  unsigned short* RG  = (unsigned short*)alloc(32ull*64*32*256*2);
  unsigned short* CB  = (unsigned short*)alloc(2048ull*1024*2);
  float*          CF  = (float*)alloc(2048ull*1024*4);

  k_detect<<<1,256,0,stream>>>((const unsigned char*)mk, flag);
  k_ln<<<2048,256,0,stream>>>(Q, lg, lb, QN);
  k_transpose<<<dim3(16,16,4),256,0,stream>>>(Wq,Wk,Wv,Wo,WQT,WKT,WVT,WOT);
  k_gather<<<2048,256,0,stream>>>(K,V,vf,KG,VG);
  k_castL<<<512,256,0,stream>>>(Lt, LB);
  k_gemm<0><<<dim3(16,8),256,0,stream>>>((const short*)QN,(const short*)WQT, QB, nullptr, nullptr);
  k_gemm<1><<<dim3(8,8),256,0,stream>>>((const short*)KG,(const short*)WKT, KB, nullptr, nullptr);
  k_gemm<2><<<dim3(8,8),256,0,stream>>>((const short*)WVT,(const short*)VG, VT, nullptr, nullptr);
  k_rel<<<1024,128,0,stream>>>((const short*)QB,(const short*)LB, vf, RG);
  k_attn<<<dim3(16,32),256,0,stream>>>((const short*)QB,(const short*)KB,(const short*)VT,
                                       (const short*)RG, mk, flag, CB, CF);
  k_gemm<3><<<dim3(16,8),256,0,stream>>>((const short*)CB,(const short*)WOT, d_out, bo, CF);
}

// Round 3
// 233.816 us; speedup vs baseline: 1.1595x; 1.1595x over previous
//
#include <hip/hip_runtime.h>
#include <stdint.h>
#include <stddef.h>

// ---------- types ----------
typedef __attribute__((ext_vector_type(8))) short s16x8;
typedef __attribute__((ext_vector_type(4))) short s16x4;
typedef __attribute__((ext_vector_type(4))) float f32x4;

#define MFMA(a,b,c) __builtin_amdgcn_mfma_f32_16x16x32_bf16((a),(b),(c),0,0,0)

static __device__ __forceinline__ unsigned short f2b(float f){
  unsigned int b = __float_as_uint(f);
  b = (b + 0x7FFFu + ((b>>16)&1u)) >> 16;     // RNE
  return (unsigned short)b;
}
static __device__ __forceinline__ float b2f(unsigned short u){
  return __uint_as_float(((unsigned int)u)<<16);
}

// B=2, T1=1024, T2=512, H=16, DH=64, DM=1024, SCALE=0.125

// ---------- mask dtype detector ----------
__global__ void k_detect(const unsigned char* __restrict__ m, int* __restrict__ flag){
  __shared__ int c1, c23;
  if(threadIdx.x==0){ c1=0; c23=0; }
  __syncthreads();
  int l1=0,l23=0;
  for(int i=threadIdx.x;i<65536;i+=256){
    if(m[i]){ int r=i&3; if(r==1) l1++; else if(r>=2) l23++; }
  }
  atomicAdd(&c1,l1); atomicAdd(&c23,l23);
  __syncthreads();
  if(threadIdx.x==0) flag[0] = c1 ? 1 : (c23 ? 2 : 0);
}

static __device__ __forceinline__ bool mload(const void* m, int flag, size_t idx){
  if(flag==0) return ((const int*)m)[idx]!=0;
  if(flag==1) return ((const unsigned char*)m)[idx]!=0;
  return ((const float*)m)[idx]!=0.f;
}

// ---------- LayerNorm(Q) -> bf16 ----------
__global__ __launch_bounds__(256) void k_ln(const float* __restrict__ Q,
    const float* __restrict__ g, const float* __restrict__ be,
    unsigned short* __restrict__ Qn){
  int row = blockIdx.x;                      // 2048
  const float4* xp = (const float4*)(Q + (size_t)row*1024);
  float4 v = xp[threadIdx.x];
  float s  = v.x+v.y+v.z+v.w;
  float s2 = v.x*v.x+v.y*v.y+v.z*v.z+v.w*v.w;
  #pragma unroll
  for(int o=1;o<64;o<<=1){ s += __shfl_xor(s,o); s2 += __shfl_xor(s2,o); }
  __shared__ float red[8];
  int w = threadIdx.x>>6, l = threadIdx.x&63;
  if(l==0){ red[w]=s; red[4+w]=s2; }
  __syncthreads();
  s  = red[0]+red[1]+red[2]+red[3];
  s2 = red[4]+red[5]+red[6]+red[7];
  float mu = s*(1.f/1024.f);
  float var = s2*(1.f/1024.f) - mu*mu;
  float rs = rsqrtf(var + 1e-5f);
  float4 gv = ((const float4*)g)[threadIdx.x];
  float4 bv = ((const float4*)be)[threadIdx.x];
  ushort4 o4;
  o4.x = f2b((v.x-mu)*rs*gv.x + bv.x);
  o4.y = f2b((v.y-mu)*rs*gv.y + bv.y);
  o4.z = f2b((v.z-mu)*rs*gv.z + bv.z);
  o4.w = f2b((v.w-mu)*rs*gv.w + bv.w);
  ((ushort4*)(Qn + (size_t)row*1024))[threadIdx.x] = o4;
}

// ---------- transpose+cast the 4 weight matrices ----------
__global__ __launch_bounds__(256) void k_transpose(
    const float* __restrict__ W0, const float* __restrict__ W1,
    const float* __restrict__ W2, const float* __restrict__ W3,
    unsigned short* __restrict__ D0, unsigned short* __restrict__ D1,
    unsigned short* __restrict__ D2, unsigned short* __restrict__ D3){
  __shared__ float tile[64][65];
  const float* S = blockIdx.z==0?W0: blockIdx.z==1?W1: blockIdx.z==2?W2:W3;
  unsigned short* D = blockIdx.z==0?D0: blockIdx.z==1?D1: blockIdx.z==2?D2:D3;
  int k0 = blockIdx.x*64, n0 = blockIdx.y*64;
  int tr = threadIdx.x>>6, tc = threadIdx.x&63;
  #pragma unroll
  for(int it=0;it<16;it++){ int r = it*4+tr; tile[r][tc] = S[(size_t)(k0+r)*1024 + n0+tc]; }
  __syncthreads();
  #pragma unroll
  for(int it=0;it<16;it++){ int r = it*4+tr; D[(size_t)(n0+r)*1024 + k0+tc] = f2b(tile[tc][r]); }
}

// ---------- gather valid_frames rows of K,V and cast to bf16 ----------
__global__ __launch_bounds__(256) void k_gather(const float* __restrict__ K,
    const float* __restrict__ V, const int* __restrict__ vf,
    unsigned short* __restrict__ Kg, unsigned short* __restrict__ Vg){
  int row = blockIdx.x;             // 0..2047
  int isV = row>>10, r = row&1023;
  int b = r>>9, jj = r&511;
  const float* src = (isV? V : K) + ((size_t)(b*1024 + vf[jj]))*1024;
  unsigned short* dst = (isV? Vg : Kg) + (size_t)r*1024;
  float4 v = ((const float4*)src)[threadIdx.x];
  ushort4 o; o.x=f2b(v.x); o.y=f2b(v.y); o.z=f2b(v.z); o.w=f2b(v.w);
  ((ushort4*)dst)[threadIdx.x] = o;
}

__global__ void k_castL(const float* __restrict__ L, unsigned short* __restrict__ Lb){
  int i = blockIdx.x*256 + threadIdx.x;
  if(i < 2047*64) Lb[i] = f2b(L[i]);
}

// ---------- merged projection GEMM: 256 blocks, runtime mode ----------
// mode0 (blocks   0..127): QB = QN @ WQT^T   (M=2048)
// mode1 (blocks 128..191): KB = KG @ WKT^T   (M=1024)
// mode2 (blocks 192..255): VT = WVT @ VG^T   (M=1024)
__global__ __launch_bounds__(256) void k_proj(
    const short* __restrict__ QN, const short* __restrict__ WQT,
    const short* __restrict__ KG, const short* __restrict__ WKT,
    const short* __restrict__ WVT, const short* __restrict__ VG,
    unsigned short* __restrict__ QB, unsigned short* __restrict__ KB,
    unsigned short* __restrict__ VT){
  __shared__ __align__(16) short Ab[128*32];
  __shared__ __align__(16) short Bb[128*32];
  int bid = blockIdx.x;
  int mode, bx;
  if(bid<128){ mode=0; bx=bid>>3; }
  else if(bid<192){ mode=1; bx=(bid-128)>>3; }
  else { mode=2; bx=(bid-192)>>3; }
  int by = bid&7;
  const short* A  = mode==0? QN : mode==1? KG : WVT;
  const short* Bt = mode==0? WQT: mode==1? WKT: VG;

  const int t = threadIdx.x;
  const int w = t>>6, l = t&63;
  const int wr = w>>1, wc = w&1;
  const int fl15 = l&15, fl4 = l>>4;
  const size_t m0 = (size_t)bx*128, n0 = (size_t)by*128;
  const int srow = t>>2, scb = t&3;
  const int sg = scb ^ ((srow>>1)&3);
  const short* Ap = A + (m0+srow)*1024 + 8*sg;
  const short* Bp = Bt + (n0+srow)*1024 + 8*sg;

  f32x4 acc[4][4];
  const f32x4 zero = {0.f,0.f,0.f,0.f};
  #pragma unroll
  for(int m=0;m<4;m++)
    #pragma unroll
    for(int n=0;n<4;n++) acc[m][n] = zero;

  for(int k0=0;k0<1024;k0+=32){
    s16x8 a0 = *(const s16x8*)(Ap + k0);
    s16x8 a1 = *(const s16x8*)(Ap + 64*1024 + k0);
    s16x8 b0 = *(const s16x8*)(Bp + k0);
    s16x8 b1 = *(const s16x8*)(Bp + 64*1024 + k0);
    __syncthreads();
    *(s16x8*)(Ab + srow*32 + scb*8)      = a0;
    *(s16x8*)(Ab + (64+srow)*32 + scb*8) = a1;
    *(s16x8*)(Bb + srow*32 + scb*8)      = b0;
    *(s16x8*)(Bb + (64+srow)*32 + scb*8) = b1;
    __syncthreads();
    s16x8 af[4], bff[4];
    #pragma unroll
    for(int m=0;m<4;m++){
      int row = wr*64 + m*16 + fl15;
      int gg = fl4 ^ ((row>>1)&3);
      af[m] = *(const s16x8*)(Ab + row*32 + gg*8);
    }
    #pragma unroll
    for(int n=0;n<4;n++){
      int row = wc*64 + n*16 + fl15;
      int gg = fl4 ^ ((row>>1)&3);
      bff[n] = *(const s16x8*)(Bb + row*32 + gg*8);
    }
    #pragma unroll
    for(int m=0;m<4;m++)
      #pragma unroll
      for(int n=0;n<4;n++)
        acc[m][n] = MFMA(af[m], bff[n], acc[m][n]);
  }

  #pragma unroll
  for(int m=0;m<4;m++){
    #pragma unroll
    for(int n=0;n<4;n++){
      int mgb = (int)m0 + wr*64 + m*16 + 4*fl4;
      int ng  = (int)n0 + wc*64 + n*16 + fl15;
      #pragma unroll
      for(int p=0;p<4;p++){
        int mg = mgb + p;
        float v = acc[m][n][p];
        if(mode==0){ int b=mg>>10, i=mg&1023, h=ng>>6, d=ng&63;
          QB[((size_t)((b*16+h)*1024+i))*64 + d] = f2b(v); }
        else if(mode==1){ int b=mg>>9, jj=mg&511, h=ng>>6, d=ng&63;
          KB[((size_t)((b*16+h)*512+jj))*64 + d] = f2b(v); }
        else { int h=mg>>6, d=mg&63, b=ng>>9, jj=ng&511;
          VT[((size_t)((b*16+h)*64+d))*512 + jj] = f2b(v); }
      }
    }
  }
}

// ---------- output GEMM ----------
__global__ __launch_bounds__(256) void k_gemmO(
    const short* __restrict__ A, const short* __restrict__ Bt,
    float* __restrict__ out, const float* __restrict__ bo,
    const float* __restrict__ ctxf){
  __shared__ __align__(16) short Ab[128*32];
  __shared__ __align__(16) short Bb[128*32];
  const int t = threadIdx.x;
  const int w = t>>6, l = t&63;
  const int wr = w>>1, wc = w&1;
  const int fl15 = l&15, fl4 = l>>4;
  const size_t m0 = (size_t)blockIdx.x*128, n0 = (size_t)blockIdx.y*128;
  const int srow = t>>2, scb = t&3;
  const int sg = scb ^ ((srow>>1)&3);
  const short* Ap = A + (m0+srow)*1024 + 8*sg;
  const short* Bp = Bt + (n0+srow)*1024 + 8*sg;

  f32x4 acc[4][4];
  const f32x4 zero = {0.f,0.f,0.f,0.f};
  #pragma unroll
  for(int m=0;m<4;m++)
    #pragma unroll
    for(int n=0;n<4;n++) acc[m][n] = zero;

  for(int k0=0;k0<1024;k0+=32){
    s16x8 a0 = *(const s16x8*)(Ap + k0);
    s16x8 a1 = *(const s16x8*)(Ap + 64*1024 + k0);
    s16x8 b0 = *(const s16x8*)(Bp + k0);
    s16x8 b1 = *(const s16x8*)(Bp + 64*1024 + k0);
    __syncthreads();
    *(s16x8*)(Ab + srow*32 + scb*8)      = a0;
    *(s16x8*)(Ab + (64+srow)*32 + scb*8) = a1;
    *(s16x8*)(Bb + srow*32 + scb*8)      = b0;
    *(s16x8*)(Bb + (64+srow)*32 + scb*8) = b1;
    __syncthreads();
    s16x8 af[4], bff[4];
    #pragma unroll
    for(int m=0;m<4;m++){
      int row = wr*64 + m*16 + fl15;
      int gg = fl4 ^ ((row>>1)&3);
      af[m] = *(const s16x8*)(Ab + row*32 + gg*8);
    }
    #pragma unroll
    for(int n=0;n<4;n++){
      int row = wc*64 + n*16 + fl15;
      int gg = fl4 ^ ((row>>1)&3);
      bff[n] = *(const s16x8*)(Bb + row*32 + gg*8);
    }
    #pragma unroll
    for(int m=0;m<4;m++)
      #pragma unroll
      for(int n=0;n<4;n++)
        acc[m][n] = MFMA(af[m], bff[n], acc[m][n]);
  }

  #pragma unroll
  for(int m=0;m<4;m++){
    #pragma unroll
    for(int n=0;n<4;n++){
      int mgb = (int)m0 + wr*64 + m*16 + 4*fl4;
      int ng  = (int)n0 + wc*64 + n*16 + fl15;
      #pragma unroll
      for(int p=0;p<4;p++){
        int mg = mgb + p;
        size_t idx = (size_t)mg*1024 + ng;
        out[idx] = acc[m][n][p] + bo[ng] + ctxf[idx];
      }
    }
  }
}

// ---------- rel: RELG[bh][qg][t][lane][p] = bf16( q_i . L[1023+vf[jj]-i] ) ----------
#define GS 536
__global__ __launch_bounds__(128) void k_rel(const short* __restrict__ qb,
    const short* __restrict__ lbf, const int* __restrict__ vf,
    unsigned short* __restrict__ relg){
  __shared__ __align__(16) short G[2][16*GS];
  __shared__ int vfs[512];
  const int t=threadIdx.x, w=t>>6, l=t&63, fl15=l&15, fl4=l>>4;
  const int bh  = blockIdx.x >> 5;
  const int qt2 = blockIdx.x & 31;
  const int qw  = qt2*32 + w*16;
  for(int i=t;i<512;i+=128) vfs[i]=vf[i];
  __syncthreads();
  const int vf0 = vfs[0];
  const int x0 = 1008 + vf0 - qw;            // >= 0
  const short* qp = qb + ((size_t)(bh*1024 + qw + fl15))*64 + 8*fl4;
  s16x8 qa0 = *(const s16x8*)qp;
  s16x8 qa1 = *(const s16x8*)(qp+32);
  short* Gw = &G[w][0];
  const f32x4 zero = {0.f,0.f,0.f,0.f};
  for(int c=0;c<2;c++){
    int xc = x0 + c*528;
    #pragma unroll 4
    for(int tt=0;tt<33;tt++){
      int xr = xc + tt*16 + fl15; if(xr>2046) xr = 2046;
      const short* lp = lbf + (size_t)xr*64 + 8*fl4;
      s16x8 b0v = *(const s16x8*)lp;
      s16x8 b1v = *(const s16x8*)(lp+32);
      f32x4 a = zero;
      a = MFMA(qa0,b0v,a); a = MFMA(qa1,b1v,a);
      #pragma unroll
      for(int p=0;p<4;p++) Gw[(4*fl4+p)*GS + tt*16 + fl15] = (short)f2b(a[p]);
    }
    __syncthreads();
    #pragma unroll 4
    for(int tt=0;tt<32;tt++){
      int jj = tt*16 + fl15;
      int xv = 1023 + vfs[jj] - qw;
      #pragma unroll
      for(int p=0;p<4;p++){
        int r = 4*fl4 + p;
        int xloc = xv - r - xc;
        if(xloc>=0 && xloc<528){
          relg[((size_t)((bh*64 + qt2*2 + w)*32 + tt))*256 + l*4 + p]
            = (unsigned short)Gw[r*GS + xloc];
        }
      }
    }
    __syncthreads();
  }
}

// ---------- flash attention: online softmax over 8 chunks of 64 keys ----------
__global__ __launch_bounds__(256,2) void k_attn(const short* __restrict__ qb,
    const short* __restrict__ kb, const short* __restrict__ vt,
    const short* __restrict__ relg, const void* __restrict__ mask,
    const int* __restrict__ flagp,
    unsigned short* __restrict__ ctxb, float* __restrict__ ctxf){
  __shared__ __align__(16) short PB[4][1024];       // 2 KiB per wave, swizzled
  __shared__ unsigned int MW[4][256];               // mask words per wave
  const int t=threadIdx.x, w=t>>6, l=t&63, fl15=l&15, fl4=l>>4;
  const int bh = blockIdx.y;       // 0..31
  const int qt = blockIdx.x;       // 0..15
  const int qw = qt*64 + w*16;
  const int qg = qt*4 + w;
  const int flag = *flagp;
  short* Pw = &PB[w][0];
  unsigned int* mw = &MW[w][0];

  // --- pack mask bits via ballot ---
  for(int r=0;r<16;r++){
    size_t mbase = ((size_t)(bh*1024 + qw + r))*512;
    #pragma unroll
    for(int c=0;c<8;c++){
      bool mk = mload(mask, flag, mbase + c*64 + l);
      unsigned long long bal = __ballot(mk);
      if(l==0){ mw[r*16 + c*2] = (unsigned int)bal; mw[r*16 + c*2 + 1] = (unsigned int)(bal>>32); }
    }
  }
  unsigned int mbits[4];
  #pragma unroll
  for(int p=0;p<4;p++){
    int r = 4*fl4+p;
    unsigned int bs = 0;
    #pragma unroll
    for(int u=0;u<16;u++){
      unsigned int wv = mw[r*16+u];
      bs |= ((wv>>fl15)&1u) << (2*u);
      bs |= ((wv>>(16+fl15))&1u) << (2*u+1);
    }
    mbits[p] = bs;
  }

  // --- q fragments ---
  const short* qp = qb + ((size_t)(bh*1024 + qw + fl15))*64 + 8*fl4;
  s16x8 qa0 = *(const s16x8*)qp;
  s16x8 qa1 = *(const s16x8*)(qp+32);

  // row pointers
  const short* kp_row = kb + ((size_t)(bh*512 + fl15))*64 + 8*fl4;   // + tt*1024
  const short* rp     = relg + ((size_t)(bh*64+qg))*32*256 + l*4;    // + tt*256
  const short* vp[4];
  #pragma unroll
  for(int dt=0;dt<4;dt++) vp[dt] = vt + ((size_t)(bh*64 + dt*16 + fl15))*512 + 8*fl4;

  const f32x4 zero = {0.f,0.f,0.f,0.f};
  f32x4 facc[4];               // [dt], rows p = queries 4*fl4+p, col dt*16+fl15
  #pragma unroll
  for(int dt=0;dt<4;dt++) facc[dt] = zero;
  float m_run[4] = {-1e30f,-1e30f,-1e30f,-1e30f};
  float ps[4]    = {0.f,0.f,0.f,0.f};

  // K/rel double buffer
  s16x8 kf[2][8];
  s16x4 rf[2][4];
  #pragma unroll
  for(int tl=0;tl<4;tl++){
    const short* ka = kp_row + (size_t)tl*1024;
    kf[0][2*tl]   = *(const s16x8*)ka;
    kf[0][2*tl+1] = *(const s16x8*)(ka+32);
    rf[0][tl]     = *(const s16x4*)(rp + tl*256);
  }

  #pragma unroll
  for(int c=0;c<8;c++){
    const int cur = c&1, nxt = cur^1;
    if(c<7){
      #pragma unroll
      for(int tl=0;tl<4;tl++){
        const short* ka = kp_row + (size_t)(4*(c+1)+tl)*1024;
        kf[nxt][2*tl]   = *(const s16x8*)ka;
        kf[nxt][2*tl+1] = *(const s16x8*)(ka+32);
        rf[nxt][tl]     = *(const s16x4*)(rp + (size_t)(4*(c+1)+tl)*256);
      }
    }
    // V fragments for this chunk
    s16x8 vfr[8];
    #pragma unroll
    for(int dt=0;dt<4;dt++){
      vfr[2*dt]   = *(const s16x8*)(vp[dt] + c*64);
      vfr[2*dt+1] = *(const s16x8*)(vp[dt] + c*64 + 32);
    }

    // QK^T + rel + mask
    f32x4 S[4];
    #pragma unroll
    for(int tl=0;tl<4;tl++){
      f32x4 a = zero;
      a = MFMA(qa0, kf[cur][2*tl], a);
      a = MFMA(qa1, kf[cur][2*tl+1], a);
      #pragma unroll
      for(int p=0;p<4;p++){
        float sv = (a[p] + b2f((unsigned short)rf[cur][tl][p])) * 0.125f;
        bool mskb = (mbits[p]>>(4*c+tl))&1u;
        a[p] = mskb ? -1e30f : sv;
      }
      S[tl] = a;
    }

    // chunk max per row, rescale
    float cm[4];
    #pragma unroll
    for(int p=0;p<4;p++){
      cm[p] = fmaxf(fmaxf(S[0][p],S[1][p]), fmaxf(S[2][p],S[3][p]));
      #pragma unroll
      for(int o=1;o<16;o<<=1) cm[p] = fmaxf(cm[p], __shfl_xor(cm[p],o));
      float mn = fmaxf(m_run[p], cm[p]);
      float fac = __expf(m_run[p]-mn);
      m_run[p] = mn;
      ps[p] *= fac;
      #pragma unroll
      for(int dt=0;dt<4;dt++) facc[dt][p] *= fac;
    }

    // exp + write P chunk to wave-private LDS (swizzled)
    #pragma unroll
    for(int tl=0;tl<4;tl++){
      #pragma unroll
      for(int p=0;p<4;p++){
        float e = __expf(S[tl][p]-m_run[p]);
        ps[p] += e;
        int row = 4*fl4+p;
        Pw[row*64 + ((tl*16 + fl15) ^ (fl4<<4))] = (short)f2b(e);
      }
    }

    // PV accumulate
    #pragma unroll
    for(int s=0;s<2;s++){
      s16x8 pa = *(const s16x8*)(Pw + fl15*64 + ((s*32 + fl4*8) ^ ((fl15>>2)<<4)));
      #pragma unroll
      for(int dt=0;dt<4;dt++)
        facc[dt] = MFMA(pa, vfr[2*dt+s], facc[dt]);
    }
  }

  // final normalize + store
  float inv[4];
  #pragma unroll
  for(int p=0;p<4;p++){
    float sm = ps[p];
    #pragma unroll
    for(int o=1;o<16;o<<=1) sm += __shfl_xor(sm,o);
    inv[p] = 1.f/sm;
  }
  const int b = bh>>4, h = bh&15;
  const int irow0 = qw + 4*fl4;
  #pragma unroll
  for(int dt=0;dt<4;dt++){
    #pragma unroll
    for(int p=0;p<4;p++){
      float val = facc[dt][p] * inv[p];
      size_t idx = ((size_t)(b*1024 + irow0 + p))*1024 + h*64 + dt*16 + fl15;
      ctxb[idx] = f2b(val);
      ctxf[idx] = val;
    }
  }
}

// ---------- launch ----------
extern "C" void kernel_launch(void* const* d_in, const int* in_sizes, int n_in,
                              void* d_out, int out_size, void* d_ws, size_t ws_size,
                              hipStream_t stream){
  (void)in_sizes; (void)n_in; (void)out_size; (void)ws_size;
  const float* Q  = (const float*)d_in[0];
  const float* K  = (const float*)d_in[1];
  const float* V  = (const float*)d_in[2];
  const float* Lt = (const float*)d_in[3];
  const int*   vf = (const int*)d_in[4];
  const void*  mk = d_in[5];
  const float* Wq = (const float*)d_in[6];
  const float* Wk = (const float*)d_in[7];
  const float* Wv = (const float*)d_in[8];
  const float* Wo = (const float*)d_in[9];
  const float* bo = (const float*)d_in[10];
  const float* lg = (const float*)d_in[11];
  const float* lb = (const float*)d_in[12];

  char* base = (char*)d_ws;
  size_t off = 0;
  auto alloc = [&](size_t bytes)->char*{
    char* p = base + off; off += (bytes + 255) & ~(size_t)255; return p; };
  int* flag           = (int*)alloc(256);
  unsigned short* QN  = (unsigned short*)alloc(2048ull*1024*2);
  unsigned short* KG  = (unsigned short*)alloc(1024ull*1024*2);
  unsigned short* VG  = (unsigned short*)alloc(1024ull*1024*2);
  unsigned short* WQT = (unsigned short*)alloc(1024ull*1024*2);
  unsigned short* WKT = (unsigned short*)alloc(1024ull*1024*2);
  unsigned short* WVT = (unsigned short*)alloc(1024ull*1024*2);
  unsigned short* WOT = (unsigned short*)alloc(1024ull*1024*2);
  unsigned short* LB  = (unsigned short*)alloc(2047ull*64*2);
  unsigned short* QB  = (unsigned short*)alloc(32ull*1024*64*2);
  unsigned short* KB  = (unsigned short*)alloc(32ull*512*64*2);
  unsigned short* VT  = (unsigned short*)alloc(32ull*64*512*2);
  unsigned short* RG  = (unsigned short*)alloc(32ull*64*32*256*2);
  unsigned short* CB  = (unsigned short*)alloc(2048ull*1024*2);
  float*          CF  = (float*)alloc(2048ull*1024*4);

  k_detect<<<1,256,0,stream>>>((const unsigned char*)mk, flag);
  k_ln<<<2048,256,0,stream>>>(Q, lg, lb, QN);
  k_transpose<<<dim3(16,16,4),256,0,stream>>>(Wq,Wk,Wv,Wo,WQT,WKT,WVT,WOT);
  k_gather<<<2048,256,0,stream>>>(K,V,vf,KG,VG);
  k_castL<<<512,256,0,stream>>>(Lt, LB);
  k_proj<<<256,256,0,stream>>>((const short*)QN,(const short*)WQT,
                               (const short*)KG,(const short*)WKT,
                               (const short*)WVT,(const short*)VG,
                               QB, KB, VT);
  k_rel<<<1024,128,0,stream>>>((const short*)QB,(const short*)LB, vf, RG);
  k_attn<<<dim3(16,32),256,0,stream>>>((const short*)QB,(const short*)KB,(const short*)VT,
                                       (const short*)RG, mk, flag, CB, CF);
  k_gemmO<<<dim3(16,8),256,0,stream>>>((const short*)CB,(const short*)WOT,
                                       (float*)d_out, bo, CF);
}

// Round 4
// 158.168 us; speedup vs baseline: 1.7140x; 1.4783x over previous
//
#include <hip/hip_runtime.h>
#include <stdint.h>
#include <stddef.h>

// ---------- types ----------
typedef __attribute__((ext_vector_type(8))) short s16x8;
typedef __attribute__((ext_vector_type(4))) short s16x4;
typedef __attribute__((ext_vector_type(4))) float f32x4;

#define MFMA(a,b,c) __builtin_amdgcn_mfma_f32_16x16x32_bf16((a),(b),(c),0,0,0)

static __device__ __forceinline__ unsigned short f2b(float f){
  unsigned int b = __float_as_uint(f);
  b = (b + 0x7FFFu + ((b>>16)&1u)) >> 16;     // RNE
  return (unsigned short)b;
}
static __device__ __forceinline__ float b2f(unsigned short u){
  return __uint_as_float(((unsigned int)u)<<16);
}

// B=2, T1=1024, T2=512, H=16, DH=64, DM=1024, SCALE=0.125

// ---------- mask pre-pack: MB[rowgrp][f][p] words, bit i = mask[row][i*16+f] ----------
// local dtype detection per block (all-zero region -> words 0 under any dtype: safe)
__global__ __launch_bounds__(256) void k_mask(const unsigned char* __restrict__ m,
    unsigned int* __restrict__ MB){
  const int t = threadIdx.x;
  const size_t g0 = (size_t)blockIdx.x*16;          // first of 16 global rows (32768 total)
  // --- detect dtype on bytes [g0*512, g0*512+8192) (always in-bounds) ---
  __shared__ int cnt1, cnt23;
  if(t==0){ cnt1=0; cnt23=0; }
  __syncthreads();
  const uint4* bp = (const uint4*)(m + g0*512);
  int l1=0,l23=0;
  #pragma unroll
  for(int i=0;i<2;i++){
    uint4 v = bp[t + i*256];
    unsigned int ws[4] = {v.x,v.y,v.z,v.w};
    #pragma unroll
    for(int j=0;j<4;j++){
      if((ws[j]>>8)&0xFFu) l1++;
      if(ws[j]>>16)        l23++;
    }
  }
  #pragma unroll
  for(int o=1;o<64;o<<=1){ l1 += __shfl_xor(l1,o); l23 += __shfl_xor(l23,o); }
  if((t&63)==0){ atomicAdd(&cnt1,l1); atomicAdd(&cnt23,l23); }
  __syncthreads();
  const int flag = cnt1 ? 1 : (cnt23 ? 2 : 0);

  // --- pack: thread (r = g0 + t>>4, f = t&15) builds 32-bit word ---
  const int rl = t>>4, f = t&15;
  const size_t base = (g0 + rl)*512 + f;
  unsigned int word = 0;
  if(flag==0){
    const int* p = (const int*)m;
    #pragma unroll
    for(int i=0;i<32;i++) word |= (p[base+i*16]!=0 ? 1u:0u) << i;
  } else if(flag==1){
    #pragma unroll
    for(int i=0;i<32;i++) word |= (m[base+i*16]!=0 ? 1u:0u) << i;
  } else {
    const float* p = (const float*)m;
    #pragma unroll
    for(int i=0;i<32;i++) word |= (p[base+i*16]!=0.f ? 1u:0u) << i;
  }
  // rowgrp = blockIdx.x*4 + (t>>6);  layout [rowgrp][f][r&3]
  MB[((size_t)blockIdx.x*4 + (t>>6))*64 + f*4 + (rl&3)] = word;
}

// ---------- fused prep: LN(Q), gather K/V, cast L, transpose 4 weights ----------
__global__ __launch_bounds__(256) void k_prep(
    const float* __restrict__ Q, const float* __restrict__ g, const float* __restrict__ be,
    unsigned short* __restrict__ Qn,
    const float* __restrict__ K, const float* __restrict__ V, const int* __restrict__ vf,
    unsigned short* __restrict__ Kg, unsigned short* __restrict__ Vg,
    const float* __restrict__ L, unsigned short* __restrict__ Lb,
    const float* __restrict__ W0, const float* __restrict__ W1,
    const float* __restrict__ W2, const float* __restrict__ W3,
    unsigned short* __restrict__ D0, unsigned short* __restrict__ D1,
    unsigned short* __restrict__ D2, unsigned short* __restrict__ D3){
  __shared__ float tile[64][65];
  __shared__ float red[8];
  const int bid = blockIdx.x, t = threadIdx.x;
  if(bid < 2048){                       // ---- LayerNorm ----
    const float4* xp = (const float4*)(Q + (size_t)bid*1024);
    float4 v = xp[t];
    float s  = v.x+v.y+v.z+v.w;
    float s2 = v.x*v.x+v.y*v.y+v.z*v.z+v.w*v.w;
    #pragma unroll
    for(int o=1;o<64;o<<=1){ s += __shfl_xor(s,o); s2 += __shfl_xor(s2,o); }
    int w = t>>6, l = t&63;
    if(l==0){ red[w]=s; red[4+w]=s2; }
    __syncthreads();
    s  = red[0]+red[1]+red[2]+red[3];
    s2 = red[4]+red[5]+red[6]+red[7];
    float mu = s*(1.f/1024.f);
    float var = s2*(1.f/1024.f) - mu*mu;
    float rs = rsqrtf(var + 1e-5f);
    float4 gv = ((const float4*)g)[t];
    float4 bv = ((const float4*)be)[t];
    ushort4 o4;
    o4.x = f2b((v.x-mu)*rs*gv.x + bv.x);
    o4.y = f2b((v.y-mu)*rs*gv.y + bv.y);
    o4.z = f2b((v.z-mu)*rs*gv.z + bv.z);
    o4.w = f2b((v.w-mu)*rs*gv.w + bv.w);
    ((ushort4*)(Qn + (size_t)bid*1024))[t] = o4;
  } else if(bid < 4096){                // ---- gather K/V ----
    int row = bid - 2048;               // 0..2047
    int isV = row>>10, r = row&1023;
    int b = r>>9, jj = r&511;
    const float* src = (isV? V : K) + ((size_t)(b*1024 + vf[jj]))*1024;
    unsigned short* dst = (isV? Vg : Kg) + (size_t)r*1024;
    float4 v = ((const float4*)src)[t];
    ushort4 o; o.x=f2b(v.x); o.y=f2b(v.y); o.z=f2b(v.z); o.w=f2b(v.w);
    ((ushort4*)dst)[t] = o;
  } else if(bid < 4608){                // ---- cast lookup table ----
    int i = (bid-4096)*256 + t;
    if(i < 2047*64) Lb[i] = f2b(L[i]);
  } else {                              // ---- weight transpose ----
    int idx = bid - 4608;               // 0..1023
    int z = idx>>8, rem = idx&255;
    int k0 = (rem&15)*64, n0 = (rem>>4)*64;
    const float* S = z==0?W0: z==1?W1: z==2?W2:W3;
    unsigned short* D = z==0?D0: z==1?D1: z==2?D2:D3;
    int tr = t>>6, tc = t&63;
    #pragma unroll
    for(int it=0;it<16;it++){ int r = it*4+tr; tile[r][tc] = S[(size_t)(k0+r)*1024 + n0+tc]; }
    __syncthreads();
    #pragma unroll
    for(int it=0;it<16;it++){ int r = it*4+tr; D[(size_t)(n0+r)*1024 + k0+tc] = f2b(tile[tc][r]); }
  }
}

// ---------- merged projection GEMM: 256 blocks, runtime mode ----------
__global__ __launch_bounds__(256) void k_proj(
    const short* __restrict__ QN, const short* __restrict__ WQT,
    const short* __restrict__ KG, const short* __restrict__ WKT,
    const short* __restrict__ WVT, const short* __restrict__ VG,
    unsigned short* __restrict__ QB, unsigned short* __restrict__ KB,
    unsigned short* __restrict__ VT){
  __shared__ __align__(16) short Ab[128*32];
  __shared__ __align__(16) short Bb[128*32];
  int bid = blockIdx.x;
  int mode, bx;
  if(bid<128){ mode=0; bx=bid>>3; }
  else if(bid<192){ mode=1; bx=(bid-128)>>3; }
  else { mode=2; bx=(bid-192)>>3; }
  int by = bid&7;
  const short* A  = mode==0? QN : mode==1? KG : WVT;
  const short* Bt = mode==0? WQT: mode==1? WKT: VG;

  const int t = threadIdx.x;
  const int w = t>>6, l = t&63;
  const int wr = w>>1, wc = w&1;
  const int fl15 = l&15, fl4 = l>>4;
  const size_t m0 = (size_t)bx*128, n0 = (size_t)by*128;
  const int srow = t>>2, scb = t&3;
  const int sg = scb ^ ((srow>>1)&3);
  const short* Ap = A + (m0+srow)*1024 + 8*sg;
  const short* Bp = Bt + (n0+srow)*1024 + 8*sg;

  f32x4 acc[4][4];
  const f32x4 zero = {0.f,0.f,0.f,0.f};
  #pragma unroll
  for(int m=0;m<4;m++)
    #pragma unroll
    for(int n=0;n<4;n++) acc[m][n] = zero;

  for(int k0=0;k0<1024;k0+=32){
    s16x8 a0 = *(const s16x8*)(Ap + k0);
    s16x8 a1 = *(const s16x8*)(Ap + 64*1024 + k0);
    s16x8 b0 = *(const s16x8*)(Bp + k0);
    s16x8 b1 = *(const s16x8*)(Bp + 64*1024 + k0);
    __syncthreads();
    *(s16x8*)(Ab + srow*32 + scb*8)      = a0;
    *(s16x8*)(Ab + (64+srow)*32 + scb*8) = a1;
    *(s16x8*)(Bb + srow*32 + scb*8)      = b0;
    *(s16x8*)(Bb + (64+srow)*32 + scb*8) = b1;
    __syncthreads();
    s16x8 af[4], bff[4];
    #pragma unroll
    for(int m=0;m<4;m++){
      int row = wr*64 + m*16 + fl15;
      int gg = fl4 ^ ((row>>1)&3);
      af[m] = *(const s16x8*)(Ab + row*32 + gg*8);
    }
    #pragma unroll
    for(int n=0;n<4;n++){
      int row = wc*64 + n*16 + fl15;
      int gg = fl4 ^ ((row>>1)&3);
      bff[n] = *(const s16x8*)(Bb + row*32 + gg*8);
    }
    #pragma unroll
    for(int m=0;m<4;m++)
      #pragma unroll
      for(int n=0;n<4;n++)
        acc[m][n] = MFMA(af[m], bff[n], acc[m][n]);
  }

  #pragma unroll
  for(int m=0;m<4;m++){
    #pragma unroll
    for(int n=0;n<4;n++){
      int mgb = (int)m0 + wr*64 + m*16 + 4*fl4;
      int ng  = (int)n0 + wc*64 + n*16 + fl15;
      #pragma unroll
      for(int p=0;p<4;p++){
        int mg = mgb + p;
        float v = acc[m][n][p];
        if(mode==0){ int b=mg>>10, i=mg&1023, h=ng>>6, d=ng&63;
          QB[((size_t)((b*16+h)*1024+i))*64 + d] = f2b(v); }
        else if(mode==1){ int b=mg>>9, jj=mg&511, h=ng>>6, d=ng&63;
          KB[((size_t)((b*16+h)*512+jj))*64 + d] = f2b(v); }
        else { int h=mg>>6, d=mg&63, b=ng>>9, jj=ng&511;
          VT[((size_t)((b*16+h)*64+d))*512 + jj] = f2b(v); }
      }
    }
  }
}

// ---------- output GEMM ----------
__global__ __launch_bounds__(256) void k_gemmO(
    const short* __restrict__ A, const short* __restrict__ Bt,
    float* __restrict__ out, const float* __restrict__ bo,
    const float* __restrict__ ctxf){
  __shared__ __align__(16) short Ab[128*32];
  __shared__ __align__(16) short Bb[128*32];
  const int t = threadIdx.x;
  const int w = t>>6, l = t&63;
  const int wr = w>>1, wc = w&1;
  const int fl15 = l&15, fl4 = l>>4;
  const size_t m0 = (size_t)blockIdx.x*128, n0 = (size_t)blockIdx.y*128;
  const int srow = t>>2, scb = t&3;
  const int sg = scb ^ ((srow>>1)&3);
  const short* Ap = A + (m0+srow)*1024 + 8*sg;
  const short* Bp = Bt + (n0+srow)*1024 + 8*sg;

  f32x4 acc[4][4];
  const f32x4 zero = {0.f,0.f,0.f,0.f};
  #pragma unroll
  for(int m=0;m<4;m++)
    #pragma unroll
    for(int n=0;n<4;n++) acc[m][n] = zero;

  for(int k0=0;k0<1024;k0+=32){
    s16x8 a0 = *(const s16x8*)(Ap + k0);
    s16x8 a1 = *(const s16x8*)(Ap + 64*1024 + k0);
    s16x8 b0 = *(const s16x8*)(Bp + k0);
    s16x8 b1 = *(const s16x8*)(Bp + 64*1024 + k0);
    __syncthreads();
    *(s16x8*)(Ab + srow*32 + scb*8)      = a0;
    *(s16x8*)(Ab + (64+srow)*32 + scb*8) = a1;
    *(s16x8*)(Bb + srow*32 + scb*8)      = b0;
    *(s16x8*)(Bb + (64+srow)*32 + scb*8) = b1;
    __syncthreads();
    s16x8 af[4], bff[4];
    #pragma unroll
    for(int m=0;m<4;m++){
      int row = wr*64 + m*16 + fl15;
      int gg = fl4 ^ ((row>>1)&3);
      af[m] = *(const s16x8*)(Ab + row*32 + gg*8);
    }
    #pragma unroll
    for(int n=0;n<4;n++){
      int row = wc*64 + n*16 + fl15;
      int gg = fl4 ^ ((row>>1)&3);
      bff[n] = *(const s16x8*)(Bb + row*32 + gg*8);
    }
    #pragma unroll
    for(int m=0;m<4;m++)
      #pragma unroll
      for(int n=0;n<4;n++)
        acc[m][n] = MFMA(af[m], bff[n], acc[m][n]);
  }

  #pragma unroll
  for(int m=0;m<4;m++){
    #pragma unroll
    for(int n=0;n<4;n++){
      int mgb = (int)m0 + wr*64 + m*16 + 4*fl4;
      int ng  = (int)n0 + wc*64 + n*16 + fl15;
      #pragma unroll
      for(int p=0;p<4;p++){
        int mg = mgb + p;
        size_t idx = (size_t)mg*1024 + ng;
        out[idx] = acc[m][n][p] + bo[ng] + ctxf[idx];
      }
    }
  }
}

// ---------- rel: RELG[bh][qg][t][lane][p] = bf16( q_i . L[1023+vf[jj]-i] ) ----------
#define GS 536
__global__ __launch_bounds__(128) void k_rel(const short* __restrict__ qb,
    const short* __restrict__ lbf, const int* __restrict__ vf,
    unsigned short* __restrict__ relg){
  __shared__ __align__(16) short G[2][16*GS];
  __shared__ int vfs[512];
  const int t=threadIdx.x, w=t>>6, l=t&63, fl15=l&15, fl4=l>>4;
  const int bh  = blockIdx.x >> 5;
  const int qt2 = blockIdx.x & 31;
  const int qw  = qt2*32 + w*16;
  for(int i=t;i<512;i+=128) vfs[i]=vf[i];
  __syncthreads();
  const int vf0 = vfs[0];
  const int x0 = 1008 + vf0 - qw;            // >= 0
  const short* qp = qb + ((size_t)(bh*1024 + qw + fl15))*64 + 8*fl4;
  s16x8 qa0 = *(const s16x8*)qp;
  s16x8 qa1 = *(const s16x8*)(qp+32);
  short* Gw = &G[w][0];
  const f32x4 zero = {0.f,0.f,0.f,0.f};
  for(int c=0;c<2;c++){
    int xc = x0 + c*528;
    #pragma unroll 4
    for(int tt=0;tt<33;tt++){
      int xr = xc + tt*16 + fl15; if(xr>2046) xr = 2046;
      const short* lp = lbf + (size_t)xr*64 + 8*fl4;
      s16x8 b0v = *(const s16x8*)lp;
      s16x8 b1v = *(const s16x8*)(lp+32);
      f32x4 a = zero;
      a = MFMA(qa0,b0v,a); a = MFMA(qa1,b1v,a);
      #pragma unroll
      for(int p=0;p<4;p++) Gw[(4*fl4+p)*GS + tt*16 + fl15] = (short)f2b(a[p]);
    }
    __syncthreads();
    #pragma unroll 4
    for(int tt=0;tt<32;tt++){
      int jj = tt*16 + fl15;
      int xv = 1023 + vfs[jj] - qw;
      #pragma unroll
      for(int p=0;p<4;p++){
        int r = 4*fl4 + p;
        int xloc = xv - r - xc;
        if(xloc>=0 && xloc<528){
          relg[((size_t)((bh*64 + qt2*2 + w)*32 + tt))*256 + l*4 + p]
            = (unsigned short)Gw[r*GS + xloc];
        }
      }
    }
    __syncthreads();
  }
}

// ---------- flash attention: online softmax over 8 chunks of 64 keys ----------
__global__ __launch_bounds__(256,2) void k_attn(const short* __restrict__ qb,
    const short* __restrict__ kb, const short* __restrict__ vt,
    const short* __restrict__ relg, const unsigned int* __restrict__ MB,
    unsigned short* __restrict__ ctxb, float* __restrict__ ctxf){
  __shared__ __align__(16) short PB[4][1024];       // 2 KiB per wave, swizzled
  const int t=threadIdx.x, w=t>>6, l=t&63, fl15=l&15, fl4=l>>4;
  const int bh = blockIdx.y;       // 0..31
  const int qt = blockIdx.x;       // 0..15
  const int qw = qt*64 + w*16;
  const int qg = qt*4 + w;
  short* Pw = &PB[w][0];

  // --- mask bits: one uint4 per lane ---
  const int rowgrp = bh*256 + qt*16 + w*4 + fl4;
  uint4 mv = ((const uint4*)MB)[rowgrp*16 + fl15];
  unsigned int mbits[4] = {mv.x, mv.y, mv.z, mv.w};

  // --- q fragments ---
  const short* qp = qb + ((size_t)(bh*1024 + qw + fl15))*64 + 8*fl4;
  s16x8 qa0 = *(const s16x8*)qp;
  s16x8 qa1 = *(const s16x8*)(qp+32);

  // row pointers
  const short* kp_row = kb + ((size_t)(bh*512 + fl15))*64 + 8*fl4;   // + tt*1024
  const short* rp     = relg + ((size_t)(bh*64+qg))*32*256 + l*4;    // + tt*256
  const short* vp[4];
  #pragma unroll
  for(int dt=0;dt<4;dt++) vp[dt] = vt + ((size_t)(bh*64 + dt*16 + fl15))*512 + 8*fl4;

  const f32x4 zero = {0.f,0.f,0.f,0.f};
  f32x4 facc[4];               // [dt], rows p = queries 4*fl4+p, col dt*16+fl15
  #pragma unroll
  for(int dt=0;dt<4;dt++) facc[dt] = zero;
  float m_run[4] = {-1e30f,-1e30f,-1e30f,-1e30f};
  float ps[4]    = {0.f,0.f,0.f,0.f};

  // K/rel double buffer
  s16x8 kf[2][8];
  s16x4 rf[2][4];
  #pragma unroll
  for(int tl=0;tl<4;tl++){
    const short* ka = kp_row + (size_t)tl*1024;
    kf[0][2*tl]   = *(const s16x8*)ka;
    kf[0][2*tl+1] = *(const s16x8*)(ka+32);
    rf[0][tl]     = *(const s16x4*)(rp + tl*256);
  }

  #pragma unroll
  for(int c=0;c<8;c++){
    const int cur = c&1, nxt = cur^1;
    if(c<7){
      #pragma unroll
      for(int tl=0;tl<4;tl++){
        const short* ka = kp_row + (size_t)(4*(c+1)+tl)*1024;
        kf[nxt][2*tl]   = *(const s16x8*)ka;
        kf[nxt][2*tl+1] = *(const s16x8*)(ka+32);
        rf[nxt][tl]     = *(const s16x4*)(rp + (size_t)(4*(c+1)+tl)*256);
      }
    }
    // V fragments for this chunk
    s16x8 vfr[8];
    #pragma unroll
    for(int dt=0;dt<4;dt++){
      vfr[2*dt]   = *(const s16x8*)(vp[dt] + c*64);
      vfr[2*dt+1] = *(const s16x8*)(vp[dt] + c*64 + 32);
    }

    // QK^T + rel + mask
    f32x4 S[4];
    #pragma unroll
    for(int tl=0;tl<4;tl++){
      f32x4 a = zero;
      a = MFMA(qa0, kf[cur][2*tl], a);
      a = MFMA(qa1, kf[cur][2*tl+1], a);
      #pragma unroll
      for(int p=0;p<4;p++){
        float sv = (a[p] + b2f((unsigned short)rf[cur][tl][p])) * 0.125f;
        bool mskb = (mbits[p]>>(4*c+tl))&1u;
        a[p] = mskb ? -1e30f : sv;
      }
      S[tl] = a;
    }

    // chunk max per row, rescale
    float cm[4];
    #pragma unroll
    for(int p=0;p<4;p++){
      cm[p] = fmaxf(fmaxf(S[0][p],S[1][p]), fmaxf(S[2][p],S[3][p]));
      #pragma unroll
      for(int o=1;o<16;o<<=1) cm[p] = fmaxf(cm[p], __shfl_xor(cm[p],o));
      float mn = fmaxf(m_run[p], cm[p]);
      float fac = __expf(m_run[p]-mn);
      m_run[p] = mn;
      ps[p] *= fac;
      #pragma unroll
      for(int dt=0;dt<4;dt++) facc[dt][p] *= fac;
    }

    // exp + write P chunk to wave-private LDS (swizzled)
    #pragma unroll
    for(int tl=0;tl<4;tl++){
      #pragma unroll
      for(int p=0;p<4;p++){
        float e = __expf(S[tl][p]-m_run[p]);
        ps[p] += e;
        int row = 4*fl4+p;
        Pw[row*64 + ((tl*16 + fl15) ^ (fl4<<4))] = (short)f2b(e);
      }
    }

    // PV accumulate
    #pragma unroll
    for(int s=0;s<2;s++){
      s16x8 pa = *(const s16x8*)(Pw + fl15*64 + ((s*32 + fl4*8) ^ ((fl15>>2)<<4)));
      #pragma unroll
      for(int dt=0;dt<4;dt++)
        facc[dt] = MFMA(pa, vfr[2*dt+s], facc[dt]);
    }
  }

  // final normalize + store
  float inv[4];
  #pragma unroll
  for(int p=0;p<4;p++){
    float sm = ps[p];
    #pragma unroll
    for(int o=1;o<16;o<<=1) sm += __shfl_xor(sm,o);
    inv[p] = 1.f/sm;
  }
  const int b = bh>>4, h = bh&15;
  const int irow0 = qw + 4*fl4;
  #pragma unroll
  for(int dt=0;dt<4;dt++){
    #pragma unroll
    for(int p=0;p<4;p++){
      float val = facc[dt][p] * inv[p];
      size_t idx = ((size_t)(b*1024 + irow0 + p))*1024 + h*64 + dt*16 + fl15;
      ctxb[idx] = f2b(val);
      ctxf[idx] = val;
    }
  }
}

// ---------- launch ----------
extern "C" void kernel_launch(void* const* d_in, const int* in_sizes, int n_in,
                              void* d_out, int out_size, void* d_ws, size_t ws_size,
                              hipStream_t stream){
  (void)in_sizes; (void)n_in; (void)out_size; (void)ws_size;
  const float* Q  = (const float*)d_in[0];
  const float* K  = (const float*)d_in[1];
  const float* V  = (const float*)d_in[2];
  const float* Lt = (const float*)d_in[3];
  const int*   vf = (const int*)d_in[4];
  const void*  mk = d_in[5];
  const float* Wq = (const float*)d_in[6];
  const float* Wk = (const float*)d_in[7];
  const float* Wv = (const float*)d_in[8];
  const float* Wo = (const float*)d_in[9];
  const float* bo = (const float*)d_in[10];
  const float* lg = (const float*)d_in[11];
  const float* lb = (const float*)d_in[12];

  char* base = (char*)d_ws;
  size_t off = 0;
  auto alloc = [&](size_t bytes)->char*{
    char* p = base + off; off += (bytes + 255) & ~(size_t)255; return p; };
  unsigned int*   MBp = (unsigned int*)alloc(32768ull*16*4);
  unsigned short* QN  = (unsigned short*)alloc(2048ull*1024*2);
  unsigned short* KG  = (unsigned short*)alloc(1024ull*1024*2);
  unsigned short* VG  = (unsigned short*)alloc(1024ull*1024*2);
  unsigned short* WQT = (unsigned short*)alloc(1024ull*1024*2);
  unsigned short* WKT = (unsigned short*)alloc(1024ull*1024*2);
  unsigned short* WVT = (unsigned short*)alloc(1024ull*1024*2);
  unsigned short* WOT = (unsigned short*)alloc(1024ull*1024*2);
  unsigned short* LB  = (unsigned short*)alloc(2047ull*64*2);
  unsigned short* QB  = (unsigned short*)alloc(32ull*1024*64*2);
  unsigned short* KB  = (unsigned short*)alloc(32ull*512*64*2);
  unsigned short* VT  = (unsigned short*)alloc(32ull*64*512*2);
  unsigned short* RG  = (unsigned short*)alloc(32ull*64*32*256*2);
  unsigned short* CB  = (unsigned short*)alloc(2048ull*1024*2);
  float*          CF  = (float*)alloc(2048ull*1024*4);

  k_mask<<<2048,256,0,stream>>>((const unsigned char*)mk, MBp);
  k_prep<<<5632,256,0,stream>>>(Q, lg, lb, QN, K, V, vf, KG, VG, Lt, LB,
                                Wq, Wk, Wv, Wo, WQT, WKT, WVT, WOT);
  k_proj<<<256,256,0,stream>>>((const short*)QN,(const short*)WQT,
                               (const short*)KG,(const short*)WKT,
                               (const short*)WVT,(const short*)VG,
                               QB, KB, VT);
  k_rel<<<1024,128,0,stream>>>((const short*)QB,(const short*)LB, vf, RG);
  k_attn<<<dim3(16,32),256,0,stream>>>((const short*)QB,(const short*)KB,(const short*)VT,
                                       (const short*)RG, MBp, CB, CF);
  k_gemmO<<<dim3(16,8),256,0,stream>>>((const short*)CB,(const short*)WOT,
                                       (float*)d_out, bo, CF);
}

// Round 5
// 149.527 us; speedup vs baseline: 1.8131x; 1.0578x over previous
//
#include <hip/hip_runtime.h>
#include <stdint.h>
#include <stddef.h>

// ---------- types ----------
typedef __attribute__((ext_vector_type(8))) short s16x8;
typedef __attribute__((ext_vector_type(4))) short s16x4;
typedef __attribute__((ext_vector_type(4))) float f32x4;

#define MFMA(a,b,c) __builtin_amdgcn_mfma_f32_16x16x32_bf16((a),(b),(c),0,0,0)

static __device__ __forceinline__ unsigned short f2b(float f){
  unsigned int b = __float_as_uint(f);
  b = (b + 0x7FFFu + ((b>>16)&1u)) >> 16;     // RNE
  return (unsigned short)b;
}
static __device__ __forceinline__ float b2f(unsigned short u){
  return __uint_as_float(((unsigned int)u)<<16);
}

// B=2, T1=1024, T2=512, H=16, DH=64, DM=1024, SCALE=0.125

// ---------- mask pre-pack: MB[rowgrp][f][p] words, bit i = mask[row][i*16+f] ----------
__global__ __launch_bounds__(256) void k_mask(const unsigned char* __restrict__ m,
    unsigned int* __restrict__ MB){
  const int t = threadIdx.x;
  const size_t g0 = (size_t)blockIdx.x*16;          // first of 16 global rows (32768 total)
  __shared__ int cnt1, cnt23;
  if(t==0){ cnt1=0; cnt23=0; }
  __syncthreads();
  const uint4* bp = (const uint4*)(m + g0*512);
  int l1=0,l23=0;
  #pragma unroll
  for(int i=0;i<2;i++){
    uint4 v = bp[t + i*256];
    unsigned int ws[4] = {v.x,v.y,v.z,v.w};
    #pragma unroll
    for(int j=0;j<4;j++){
      if((ws[j]>>8)&0xFFu) l1++;
      if(ws[j]>>16)        l23++;
    }
  }
  #pragma unroll
  for(int o=1;o<64;o<<=1){ l1 += __shfl_xor(l1,o); l23 += __shfl_xor(l23,o); }
  if((t&63)==0){ atomicAdd(&cnt1,l1); atomicAdd(&cnt23,l23); }
  __syncthreads();
  const int flag = cnt1 ? 1 : (cnt23 ? 2 : 0);

  const int rl = t>>4, f = t&15;
  const size_t base = (g0 + rl)*512 + f;
  unsigned int word = 0;
  if(flag==0){
    const int* p = (const int*)m;
    #pragma unroll
    for(int i=0;i<32;i++) word |= (p[base+i*16]!=0 ? 1u:0u) << i;
  } else if(flag==1){
    #pragma unroll
    for(int i=0;i<32;i++) word |= (m[base+i*16]!=0 ? 1u:0u) << i;
  } else {
    const float* p = (const float*)m;
    #pragma unroll
    for(int i=0;i<32;i++) word |= (p[base+i*16]!=0.f ? 1u:0u) << i;
  }
  MB[((size_t)blockIdx.x*4 + (t>>6))*64 + f*4 + (rl&3)] = word;
}

// ---------- fused prep: LN(Q), gather K/V, cast L, transpose 4 weights ----------
__global__ __launch_bounds__(256) void k_prep(
    const float* __restrict__ Q, const float* __restrict__ g, const float* __restrict__ be,
    unsigned short* __restrict__ Qn,
    const float* __restrict__ K, const float* __restrict__ V, const int* __restrict__ vf,
    unsigned short* __restrict__ Kg, unsigned short* __restrict__ Vg,
    const float* __restrict__ L, unsigned short* __restrict__ Lb,
    const float* __restrict__ W0, const float* __restrict__ W1,
    const float* __restrict__ W2, const float* __restrict__ W3,
    unsigned short* __restrict__ D0, unsigned short* __restrict__ D1,
    unsigned short* __restrict__ D2, unsigned short* __restrict__ D3){
  __shared__ float tile[64][65];
  __shared__ float red[8];
  const int bid = blockIdx.x, t = threadIdx.x;
  if(bid < 2048){                       // ---- LayerNorm ----
    const float4* xp = (const float4*)(Q + (size_t)bid*1024);
    float4 v = xp[t];
    float s  = v.x+v.y+v.z+v.w;
    float s2 = v.x*v.x+v.y*v.y+v.z*v.z+v.w*v.w;
    #pragma unroll
    for(int o=1;o<64;o<<=1){ s += __shfl_xor(s,o); s2 += __shfl_xor(s2,o); }
    int w = t>>6, l = t&63;
    if(l==0){ red[w]=s; red[4+w]=s2; }
    __syncthreads();
    s  = red[0]+red[1]+red[2]+red[3];
    s2 = red[4]+red[5]+red[6]+red[7];
    float mu = s*(1.f/1024.f);
    float var = s2*(1.f/1024.f) - mu*mu;
    float rs = rsqrtf(var + 1e-5f);
    float4 gv = ((const float4*)g)[t];
    float4 bv = ((const float4*)be)[t];
    ushort4 o4;
    o4.x = f2b((v.x-mu)*rs*gv.x + bv.x);
    o4.y = f2b((v.y-mu)*rs*gv.y + bv.y);
    o4.z = f2b((v.z-mu)*rs*gv.z + bv.z);
    o4.w = f2b((v.w-mu)*rs*gv.w + bv.w);
    ((ushort4*)(Qn + (size_t)bid*1024))[t] = o4;
  } else if(bid < 4096){                // ---- gather K/V ----
    int row = bid - 2048;               // 0..2047
    int isV = row>>10, r = row&1023;
    int b = r>>9, jj = r&511;
    const float* src = (isV? V : K) + ((size_t)(b*1024 + vf[jj]))*1024;
    unsigned short* dst = (isV? Vg : Kg) + (size_t)r*1024;
    float4 v = ((const float4*)src)[t];
    ushort4 o; o.x=f2b(v.x); o.y=f2b(v.y); o.z=f2b(v.z); o.w=f2b(v.w);
    ((ushort4*)dst)[t] = o;
  } else if(bid < 4608){                // ---- cast lookup table ----
    int i = (bid-4096)*256 + t;
    if(i < 2047*64) Lb[i] = f2b(L[i]);
  } else {                              // ---- weight transpose ----
    int idx = bid - 4608;               // 0..1023
    int z = idx>>8, rem = idx&255;
    int k0 = (rem&15)*64, n0 = (rem>>4)*64;
    const float* S = z==0?W0: z==1?W1: z==2?W2:W3;
    unsigned short* D = z==0?D0: z==1?D1: z==2?D2:D3;
    int tr = t>>6, tc = t&63;
    #pragma unroll
    for(int it=0;it<16;it++){ int r = it*4+tr; tile[r][tc] = S[(size_t)(k0+r)*1024 + n0+tc]; }
    __syncthreads();
    #pragma unroll
    for(int it=0;it<16;it++){ int r = it*4+tr; D[(size_t)(n0+r)*1024 + k0+tc] = f2b(tile[tc][r]); }
  }
}

// ---------- merged projection GEMM: 256 blocks, runtime mode ----------
__global__ __launch_bounds__(256) void k_proj(
    const short* __restrict__ QN, const short* __restrict__ WQT,
    const short* __restrict__ KG, const short* __restrict__ WKT,
    const short* __restrict__ WVT, const short* __restrict__ VG,
    unsigned short* __restrict__ QB, unsigned short* __restrict__ KB,
    unsigned short* __restrict__ VT){
  __shared__ __align__(16) short Ab[128*32];
  __shared__ __align__(16) short Bb[128*32];
  int bid = blockIdx.x;
  int mode, bx;
  if(bid<128){ mode=0; bx=bid>>3; }
  else if(bid<192){ mode=1; bx=(bid-128)>>3; }
  else { mode=2; bx=(bid-192)>>3; }
  int by = bid&7;
  const short* A  = mode==0? QN : mode==1? KG : WVT;
  const short* Bt = mode==0? WQT: mode==1? WKT: VG;

  const int t = threadIdx.x;
  const int w = t>>6, l = t&63;
  const int wr = w>>1, wc = w&1;
  const int fl15 = l&15, fl4 = l>>4;
  const size_t m0 = (size_t)bx*128, n0 = (size_t)by*128;
  const int srow = t>>2, scb = t&3;
  const int sg = scb ^ ((srow>>1)&3);
  const short* Ap = A + (m0+srow)*1024 + 8*sg;
  const short* Bp = Bt + (n0+srow)*1024 + 8*sg;

  f32x4 acc[4][4];
  const f32x4 zero = {0.f,0.f,0.f,0.f};
  #pragma unroll
  for(int m=0;m<4;m++)
    #pragma unroll
    for(int n=0;n<4;n++) acc[m][n] = zero;

  for(int k0=0;k0<1024;k0+=32){
    s16x8 a0 = *(const s16x8*)(Ap + k0);
    s16x8 a1 = *(const s16x8*)(Ap + 64*1024 + k0);
    s16x8 b0 = *(const s16x8*)(Bp + k0);
    s16x8 b1 = *(const s16x8*)(Bp + 64*1024 + k0);
    __syncthreads();
    *(s16x8*)(Ab + srow*32 + scb*8)      = a0;
    *(s16x8*)(Ab + (64+srow)*32 + scb*8) = a1;
    *(s16x8*)(Bb + srow*32 + scb*8)      = b0;
    *(s16x8*)(Bb + (64+srow)*32 + scb*8) = b1;
    __syncthreads();
    s16x8 af[4], bff[4];
    #pragma unroll
    for(int m=0;m<4;m++){
      int row = wr*64 + m*16 + fl15;
      int gg = fl4 ^ ((row>>1)&3);
      af[m] = *(const s16x8*)(Ab + row*32 + gg*8);
    }
    #pragma unroll
    for(int n=0;n<4;n++){
      int row = wc*64 + n*16 + fl15;
      int gg = fl4 ^ ((row>>1)&3);
      bff[n] = *(const s16x8*)(Bb + row*32 + gg*8);
    }
    #pragma unroll
    for(int m=0;m<4;m++)
      #pragma unroll
      for(int n=0;n<4;n++)
        acc[m][n] = MFMA(af[m], bff[n], acc[m][n]);
  }

  #pragma unroll
  for(int m=0;m<4;m++){
    #pragma unroll
    for(int n=0;n<4;n++){
      int mgb = (int)m0 + wr*64 + m*16 + 4*fl4;
      int ng  = (int)n0 + wc*64 + n*16 + fl15;
      #pragma unroll
      for(int p=0;p<4;p++){
        int mg = mgb + p;
        float v = acc[m][n][p];
        if(mode==0){ int b=mg>>10, i=mg&1023, h=ng>>6, d=ng&63;
          QB[((size_t)((b*16+h)*1024+i))*64 + d] = f2b(v); }
        else if(mode==1){ int b=mg>>9, jj=mg&511, h=ng>>6, d=ng&63;
          KB[((size_t)((b*16+h)*512+jj))*64 + d] = f2b(v); }
        else { int h=mg>>6, d=mg&63, b=ng>>9, jj=ng&511;
          VT[((size_t)((b*16+h)*64+d))*512 + jj] = f2b(v); }
      }
    }
  }
}

// ---------- output GEMM ----------
__global__ __launch_bounds__(256) void k_gemmO(
    const short* __restrict__ A, const short* __restrict__ Bt,
    float* __restrict__ out, const float* __restrict__ bo,
    const float* __restrict__ ctxf){
  __shared__ __align__(16) short Ab[128*32];
  __shared__ __align__(16) short Bb[128*32];
  const int t = threadIdx.x;
  const int w = t>>6, l = t&63;
  const int wr = w>>1, wc = w&1;
  const int fl15 = l&15, fl4 = l>>4;
  const size_t m0 = (size_t)blockIdx.x*128, n0 = (size_t)blockIdx.y*128;
  const int srow = t>>2, scb = t&3;
  const int sg = scb ^ ((srow>>1)&3);
  const short* Ap = A + (m0+srow)*1024 + 8*sg;
  const short* Bp = Bt + (n0+srow)*1024 + 8*sg;

  f32x4 acc[4][4];
  const f32x4 zero = {0.f,0.f,0.f,0.f};
  #pragma unroll
  for(int m=0;m<4;m++)
    #pragma unroll
    for(int n=0;n<4;n++) acc[m][n] = zero;

  for(int k0=0;k0<1024;k0+=32){
    s16x8 a0 = *(const s16x8*)(Ap + k0);
    s16x8 a1 = *(const s16x8*)(Ap + 64*1024 + k0);
    s16x8 b0 = *(const s16x8*)(Bp + k0);
    s16x8 b1 = *(const s16x8*)(Bp + 64*1024 + k0);
    __syncthreads();
    *(s16x8*)(Ab + srow*32 + scb*8)      = a0;
    *(s16x8*)(Ab + (64+srow)*32 + scb*8) = a1;
    *(s16x8*)(Bb + srow*32 + scb*8)      = b0;
    *(s16x8*)(Bb + (64+srow)*32 + scb*8) = b1;
    __syncthreads();
    s16x8 af[4], bff[4];
    #pragma unroll
    for(int m=0;m<4;m++){
      int row = wr*64 + m*16 + fl15;
      int gg = fl4 ^ ((row>>1)&3);
      af[m] = *(const s16x8*)(Ab + row*32 + gg*8);
    }
    #pragma unroll
    for(int n=0;n<4;n++){
      int row = wc*64 + n*16 + fl15;
      int gg = fl4 ^ ((row>>1)&3);
      bff[n] = *(const s16x8*)(Bb + row*32 + gg*8);
    }
    #pragma unroll
    for(int m=0;m<4;m++)
      #pragma unroll
      for(int n=0;n<4;n++)
        acc[m][n] = MFMA(af[m], bff[n], acc[m][n]);
  }

  #pragma unroll
  for(int m=0;m<4;m++){
    #pragma unroll
    for(int n=0;n<4;n++){
      int mgb = (int)m0 + wr*64 + m*16 + 4*fl4;
      int ng  = (int)n0 + wc*64 + n*16 + fl15;
      #pragma unroll
      for(int p=0;p<4;p++){
        int mg = mgb + p;
        size_t idx = (size_t)mg*1024 + ng;
        out[idx] = acc[m][n][p] + bo[ng] + ctxf[idx];
      }
    }
  }
}

// ---------- rel v2: skew-stored G, 4 waves = 4 x-chunks of one 16-row q-group ----------
// Gs holds value (r, x) at Gs[x - xcw + r][r]; gather G[r][xv-r] = Gs[xv-xcw][r] (b64 read).
// Wave w owns key jj iff vf[jj]-vf[0] in [256w, 256w+256); window width <= 1039 < 1024+15.
#define RCH 256
#define RGS 288
__global__ __launch_bounds__(256) void k_rel(const short* __restrict__ qb,
    const short* __restrict__ lbf, const int* __restrict__ vf,
    unsigned short* __restrict__ relg){
  __shared__ __align__(16) short Gs[4][RGS*16];   // 36 KiB
  __shared__ int vfs[512];
  const int t=threadIdx.x, w=t>>6, l=t&63, fl15=l&15, fl4=l>>4;
  const int bh = blockIdx.x >> 6;     // 0..31
  const int qg = blockIdx.x & 63;     // 0..63 (16-row group)
  const int qw = qg*16;
  for(int i=t;i<512;i+=256) vfs[i]=vf[i];
  __syncthreads();
  const int x0  = 1008 + vfs[0] - qw;             // >= 0
  const int xcw = x0 + w*RCH;
  const short* qp = qb + ((size_t)(bh*1024 + qw + fl15))*64 + 8*fl4;
  s16x8 qa0 = *(const s16x8*)qp;
  s16x8 qa1 = *(const s16x8*)(qp+32);
  short* Gw = &Gs[w][0];
  const f32x4 zero = {0.f,0.f,0.f,0.f};

  // phase 1: 17 tiles cover x in [xcw, xcw+272); store skewed (no barrier: wave-private)
  #pragma unroll 4
  for(int tt=0;tt<17;tt++){
    int xr = xcw + tt*16 + fl15; if(xr>2046) xr = 2046;
    const short* lp = lbf + (size_t)xr*64 + 8*fl4;
    s16x8 b0 = *(const s16x8*)lp;
    s16x8 b1 = *(const s16x8*)(lp+32);
    f32x4 a = zero;
    a = MFMA(qa0,b0,a); a = MFMA(qa1,b1,a);
    int cb = tt*16 + fl15 + 4*fl4;                // skewed col for p=0
    #pragma unroll
    for(int p=0;p<4;p++) Gw[(cb+p)*16 + 4*fl4 + p] = (short)f2b(a[p]);
  }

  // phase 2: per key-tile, one b64 read + one 8B global write under a single ownership test
  unsigned short* rb = relg + ((size_t)(bh*64+qg))*32*256 + l*4;
  #pragma unroll 4
  for(int tt=0;tt<32;tt++){
    int jj = tt*16 + fl15;
    int o  = vfs[jj] - vfs[0] - RCH*w;            // ownership: o in [0,256)
    if(o>=0 && o<RCH){
      s16x4 v4 = *(const s16x4*)(Gw + (o+15)*16 + 4*fl4);
      *(s16x4*)(rb + (size_t)tt*256) = v4;
    }
  }
}

// ---------- flash attention: online softmax over 8 chunks of 64 keys ----------
__global__ __launch_bounds__(256,2) void k_attn(const short* __restrict__ qb,
    const short* __restrict__ kb, const short* __restrict__ vt,
    const short* __restrict__ relg, const unsigned int* __restrict__ MB,
    unsigned short* __restrict__ ctxb, float* __restrict__ ctxf){
  __shared__ __align__(16) short PB[4][1024];       // 2 KiB per wave, swizzled
  const int t=threadIdx.x, w=t>>6, l=t&63, fl15=l&15, fl4=l>>4;
  const int bh = blockIdx.y;       // 0..31
  const int qt = blockIdx.x;       // 0..15
  const int qw = qt*64 + w*16;
  const int qg = qt*4 + w;
  short* Pw = &PB[w][0];

  // --- mask bits: one uint4 per lane ---
  const int rowgrp = bh*256 + qt*16 + w*4 + fl4;
  uint4 mv = ((const uint4*)MB)[rowgrp*16 + fl15];
  unsigned int mbits[4] = {mv.x, mv.y, mv.z, mv.w};

  // --- q fragments ---
  const short* qp = qb + ((size_t)(bh*1024 + qw + fl15))*64 + 8*fl4;
  s16x8 qa0 = *(const s16x8*)qp;
  s16x8 qa1 = *(const s16x8*)(qp+32);

  // row pointers
  const short* kp_row = kb + ((size_t)(bh*512 + fl15))*64 + 8*fl4;   // + tt*1024
  const short* rp     = relg + ((size_t)(bh*64+qg))*32*256 + l*4;    // + tt*256
  const short* vp[4];
  #pragma unroll
  for(int dt=0;dt<4;dt++) vp[dt] = vt + ((size_t)(bh*64 + dt*16 + fl15))*512 + 8*fl4;

  const f32x4 zero = {0.f,0.f,0.f,0.f};
  f32x4 facc[4];               // [dt], rows p = queries 4*fl4+p, col dt*16+fl15
  #pragma unroll
  for(int dt=0;dt<4;dt++) facc[dt] = zero;
  float m_run[4] = {-1e30f,-1e30f,-1e30f,-1e30f};
  float ps[4]    = {0.f,0.f,0.f,0.f};

  // K/rel double buffer
  s16x8 kf[2][8];
  s16x4 rf[2][4];
  #pragma unroll
  for(int tl=0;tl<4;tl++){
    const short* ka = kp_row + (size_t)tl*1024;
    kf[0][2*tl]   = *(const s16x8*)ka;
    kf[0][2*tl+1] = *(const s16x8*)(ka+32);
    rf[0][tl]     = *(const s16x4*)(rp + tl*256);
  }

  #pragma unroll
  for(int c=0;c<8;c++){
    const int cur = c&1, nxt = cur^1;
    if(c<7){
      #pragma unroll
      for(int tl=0;tl<4;tl++){
        const short* ka = kp_row + (size_t)(4*(c+1)+tl)*1024;
        kf[nxt][2*tl]   = *(const s16x8*)ka;
        kf[nxt][2*tl+1] = *(const s16x8*)(ka+32);
        rf[nxt][tl]     = *(const s16x4*)(rp + (size_t)(4*(c+1)+tl)*256);
      }
    }
    // V fragments for this chunk
    s16x8 vfr[8];
    #pragma unroll
    for(int dt=0;dt<4;dt++){
      vfr[2*dt]   = *(const s16x8*)(vp[dt] + c*64);
      vfr[2*dt+1] = *(const s16x8*)(vp[dt] + c*64 + 32);
    }

    // QK^T + rel + mask
    f32x4 S[4];
    #pragma unroll
    for(int tl=0;tl<4;tl++){
      f32x4 a = zero;
      a = MFMA(qa0, kf[cur][2*tl], a);
      a = MFMA(qa1, kf[cur][2*tl+1], a);
      #pragma unroll
      for(int p=0;p<4;p++){
        float sv = (a[p] + b2f((unsigned short)rf[cur][tl][p])) * 0.125f;
        bool mskb = (mbits[p]>>(4*c+tl))&1u;
        a[p] = mskb ? -1e30f : sv;
      }
      S[tl] = a;
    }

    // chunk max per row, rescale
    float cm[4];
    #pragma unroll
    for(int p=0;p<4;p++){
      cm[p] = fmaxf(fmaxf(S[0][p],S[1][p]), fmaxf(S[2][p],S[3][p]));
      #pragma unroll
      for(int o=1;o<16;o<<=1) cm[p] = fmaxf(cm[p], __shfl_xor(cm[p],o));
      float mn = fmaxf(m_run[p], cm[p]);
      float fac = __expf(m_run[p]-mn);
      m_run[p] = mn;
      ps[p] *= fac;
      #pragma unroll
      for(int dt=0;dt<4;dt++) facc[dt][p] *= fac;
    }

    // exp + write P chunk to wave-private LDS (swizzled)
    #pragma unroll
    for(int tl=0;tl<4;tl++){
      #pragma unroll
      for(int p=0;p<4;p++){
        float e = __expf(S[tl][p]-m_run[p]);
        ps[p] += e;
        int row = 4*fl4+p;
        Pw[row*64 + ((tl*16 + fl15) ^ (fl4<<4))] = (short)f2b(e);
      }
    }

    // PV accumulate
    #pragma unroll
    for(int s=0;s<2;s++){
      s16x8 pa = *(const s16x8*)(Pw + fl15*64 + ((s*32 + fl4*8) ^ ((fl15>>2)<<4)));
      #pragma unroll
      for(int dt=0;dt<4;dt++)
        facc[dt] = MFMA(pa, vfr[2*dt+s], facc[dt]);
    }
  }

  // final normalize + store
  float inv[4];
  #pragma unroll
  for(int p=0;p<4;p++){
    float sm = ps[p];
    #pragma unroll
    for(int o=1;o<16;o<<=1) sm += __shfl_xor(sm,o);
    inv[p] = 1.f/sm;
  }
  const int b = bh>>4, h = bh&15;
  const int irow0 = qw + 4*fl4;
  #pragma unroll
  for(int dt=0;dt<4;dt++){
    #pragma unroll
    for(int p=0;p<4;p++){
      float val = facc[dt][p] * inv[p];
      size_t idx = ((size_t)(b*1024 + irow0 + p))*1024 + h*64 + dt*16 + fl15;
      ctxb[idx] = f2b(val);
      ctxf[idx] = val;
    }
  }
}

// ---------- launch ----------
extern "C" void kernel_launch(void* const* d_in, const int* in_sizes, int n_in,
                              void* d_out, int out_size, void* d_ws, size_t ws_size,
                              hipStream_t stream){
  (void)in_sizes; (void)n_in; (void)out_size; (void)ws_size;
  const float* Q  = (const float*)d_in[0];
  const float* K  = (const float*)d_in[1];
  const float* V  = (const float*)d_in[2];
  const float* Lt = (const float*)d_in[3];
  const int*   vf = (const int*)d_in[4];
  const void*  mk = d_in[5];
  const float* Wq = (const float*)d_in[6];
  const float* Wk = (const float*)d_in[7];
  const float* Wv = (const float*)d_in[8];
  const float* Wo = (const float*)d_in[9];
  const float* bo = (const float*)d_in[10];
  const float* lg = (const float*)d_in[11];
  const float* lb = (const float*)d_in[12];

  char* base = (char*)d_ws;
  size_t off = 0;
  auto alloc = [&](size_t bytes)->char*{
    char* p = base + off; off += (bytes + 255) & ~(size_t)255; return p; };
  unsigned int*   MBp = (unsigned int*)alloc(32768ull*16*4);
  unsigned short* QN  = (unsigned short*)alloc(2048ull*1024*2);
  unsigned short* KG  = (unsigned short*)alloc(1024ull*1024*2);
  unsigned short* VG  = (unsigned short*)alloc(1024ull*1024*2);
  unsigned short* WQT = (unsigned short*)alloc(1024ull*1024*2);
  unsigned short* WKT = (unsigned short*)alloc(1024ull*1024*2);
  unsigned short* WVT = (unsigned short*)alloc(1024ull*1024*2);
  unsigned short* WOT = (unsigned short*)alloc(1024ull*1024*2);
  unsigned short* LB  = (unsigned short*)alloc(2047ull*64*2);
  unsigned short* QB  = (unsigned short*)alloc(32ull*1024*64*2);
  unsigned short* KB  = (unsigned short*)alloc(32ull*512*64*2);
  unsigned short* VT  = (unsigned short*)alloc(32ull*64*512*2);
  unsigned short* RG  = (unsigned short*)alloc(32ull*64*32*256*2);
  unsigned short* CB  = (unsigned short*)alloc(2048ull*1024*2);
  float*          CF  = (float*)alloc(2048ull*1024*4);

  k_mask<<<2048,256,0,stream>>>((const unsigned char*)mk, MBp);
  k_prep<<<5632,256,0,stream>>>(Q, lg, lb, QN, K, V, vf, KG, VG, Lt, LB,
                                Wq, Wk, Wv, Wo, WQT, WKT, WVT, WOT);
  k_proj<<<256,256,0,stream>>>((const short*)QN,(const short*)WQT,
                               (const short*)KG,(const short*)WKT,
                               (const short*)WVT,(const short*)VG,
                               QB, KB, VT);
  k_rel<<<2048,256,0,stream>>>((const short*)QB,(const short*)LB, vf, RG);
  k_attn<<<dim3(16,32),256,0,stream>>>((const short*)QB,(const short*)KB,(const short*)VT,
                                       (const short*)RG, MBp, CB, CF);
  k_gemmO<<<dim3(16,8),256,0,stream>>>((const short*)CB,(const short*)WOT,
                                       (float*)d_out, bo, CF);
}

// Round 7
// 145.985 us; speedup vs baseline: 1.8571x; 1.0243x over previous
//
#include <hip/hip_runtime.h>
#include <stdint.h>
#include <stddef.h>

// ---------- types ----------
typedef __attribute__((ext_vector_type(8))) short s16x8;
typedef __attribute__((ext_vector_type(4))) short s16x4;
typedef __attribute__((ext_vector_type(4))) float f32x4;

#define MFMA(a,b,c) __builtin_amdgcn_mfma_f32_16x16x32_bf16((a),(b),(c),0,0,0)

static __device__ __forceinline__ unsigned short f2b(float f){
  unsigned int b = __float_as_uint(f);
  b = (b + 0x7FFFu + ((b>>16)&1u)) >> 16;     // RNE
  return (unsigned short)b;
}
static __device__ __forceinline__ float b2f(unsigned short u){
  return __uint_as_float(((unsigned int)u)<<16);
}

// B=2, T1=1024, T2=512, H=16, DH=64, DM=1024, SCALE=0.125

// ---------- mask pre-pack: MB[rowgrp][f][p] words, bit i = mask[row][i*16+f] ----------
__global__ __launch_bounds__(256) void k_mask(const unsigned char* __restrict__ m,
    unsigned int* __restrict__ MB){
  const int t = threadIdx.x;
  const size_t g0 = (size_t)blockIdx.x*16;          // first of 16 global rows (32768 total)
  __shared__ int cnt1, cnt23;
  if(t==0){ cnt1=0; cnt23=0; }
  __syncthreads();
  const uint4* bp = (const uint4*)(m + g0*512);
  int l1=0,l23=0;
  #pragma unroll
  for(int i=0;i<2;i++){
    uint4 v = bp[t + i*256];
    unsigned int ws[4] = {v.x,v.y,v.z,v.w};
    #pragma unroll
    for(int j=0;j<4;j++){
      if((ws[j]>>8)&0xFFu) l1++;
      if(ws[j]>>16)        l23++;
    }
  }
  #pragma unroll
  for(int o=1;o<64;o<<=1){ l1 += __shfl_xor(l1,o); l23 += __shfl_xor(l23,o); }
  if((t&63)==0){ atomicAdd(&cnt1,l1); atomicAdd(&cnt23,l23); }
  __syncthreads();
  const int flag = cnt1 ? 1 : (cnt23 ? 2 : 0);

  const int rl = t>>4, f = t&15;
  const size_t base = (g0 + rl)*512 + f;
  unsigned int word = 0;
  if(flag==0){
    const int* p = (const int*)m;
    #pragma unroll
    for(int i=0;i<32;i++) word |= (p[base+i*16]!=0 ? 1u:0u) << i;
  } else if(flag==1){
    #pragma unroll
    for(int i=0;i<32;i++) word |= (m[base+i*16]!=0 ? 1u:0u) << i;
  } else {
    const float* p = (const float*)m;
    #pragma unroll
    for(int i=0;i<32;i++) word |= (p[base+i*16]!=0.f ? 1u:0u) << i;
  }
  MB[((size_t)blockIdx.x*4 + (t>>6))*64 + f*4 + (rl&3)] = word;
}

// ---------- fused prep: LN(Q), gather K/V, cast L, transpose 4 weights ----------
__global__ __launch_bounds__(256) void k_prep(
    const float* __restrict__ Q, const float* __restrict__ g, const float* __restrict__ be,
    unsigned short* __restrict__ Qn,
    const float* __restrict__ K, const float* __restrict__ V, const int* __restrict__ vf,
    unsigned short* __restrict__ Kg, unsigned short* __restrict__ Vg,
    const float* __restrict__ L, unsigned short* __restrict__ Lb,
    const float* __restrict__ W0, const float* __restrict__ W1,
    const float* __restrict__ W2, const float* __restrict__ W3,
    unsigned short* __restrict__ D0, unsigned short* __restrict__ D1,
    unsigned short* __restrict__ D2, unsigned short* __restrict__ D3){
  __shared__ float tile[64][65];
  __shared__ float red[8];
  const int bid = blockIdx.x, t = threadIdx.x;
  if(bid < 2048){                       // ---- LayerNorm ----
    const float4* xp = (const float4*)(Q + (size_t)bid*1024);
    float4 v = xp[t];
    float s  = v.x+v.y+v.z+v.w;
    float s2 = v.x*v.x+v.y*v.y+v.z*v.z+v.w*v.w;
    #pragma unroll
    for(int o=1;o<64;o<<=1){ s += __shfl_xor(s,o); s2 += __shfl_xor(s2,o); }
    int w = t>>6, l = t&63;
    if(l==0){ red[w]=s; red[4+w]=s2; }
    __syncthreads();
    s  = red[0]+red[1]+red[2]+red[3];
    s2 = red[4]+red[5]+red[6]+red[7];
    float mu = s*(1.f/1024.f);
    float var = s2*(1.f/1024.f) - mu*mu;
    float rs = rsqrtf(var + 1e-5f);
    float4 gv = ((const float4*)g)[t];
    float4 bv = ((const float4*)be)[t];
    ushort4 o4;
    o4.x = f2b((v.x-mu)*rs*gv.x + bv.x);
    o4.y = f2b((v.y-mu)*rs*gv.y + bv.y);
    o4.z = f2b((v.z-mu)*rs*gv.z + bv.z);
    o4.w = f2b((v.w-mu)*rs*gv.w + bv.w);
    ((ushort4*)(Qn + (size_t)bid*1024))[t] = o4;
  } else if(bid < 4096){                // ---- gather K/V ----
    int row = bid - 2048;               // 0..2047
    int isV = row>>10, r = row&1023;
    int b = r>>9, jj = r&511;
    const float* src = (isV? V : K) + ((size_t)(b*1024 + vf[jj]))*1024;
    unsigned short* dst = (isV? Vg : Kg) + (size_t)r*1024;
    float4 v = ((const float4*)src)[t];
    ushort4 o; o.x=f2b(v.x); o.y=f2b(v.y); o.z=f2b(v.z); o.w=f2b(v.w);
    ((ushort4*)dst)[t] = o;
  } else if(bid < 4608){                // ---- cast lookup table ----
    int i = (bid-4096)*256 + t;
    if(i < 2047*64) Lb[i] = f2b(L[i]);
  } else {                              // ---- weight transpose ----
    int idx = bid - 4608;               // 0..1023
    int z = idx>>8, rem = idx&255;
    int k0 = (rem&15)*64, n0 = (rem>>4)*64;
    const float* S = z==0?W0: z==1?W1: z==2?W2:W3;
    unsigned short* D = z==0?D0: z==1?D1: z==2?D2:D3;
    int tr = t>>6, tc = t&63;
    #pragma unroll
    for(int it=0;it<16;it++){ int r = it*4+tr; tile[r][tc] = S[(size_t)(k0+r)*1024 + n0+tc]; }
    __syncthreads();
    #pragma unroll
    for(int it=0;it<16;it++){ int r = it*4+tr; D[(size_t)(n0+r)*1024 + k0+tc] = f2b(tile[tc][r]); }
  }
}

// ---------- merged projection GEMM: 256 blocks, runtime mode ----------
__global__ __launch_bounds__(256) void k_proj(
    const short* __restrict__ QN, const short* __restrict__ WQT,
    const short* __restrict__ KG, const short* __restrict__ WKT,
    const short* __restrict__ WVT, const short* __restrict__ VG,
    unsigned short* __restrict__ QB, unsigned short* __restrict__ KB,
    unsigned short* __restrict__ VT){
  __shared__ __align__(16) short Ab[128*32];
  __shared__ __align__(16) short Bb[128*32];
  int bid = blockIdx.x;
  int mode, bx;
  if(bid<128){ mode=0; bx=bid>>3; }
  else if(bid<192){ mode=1; bx=(bid-128)>>3; }
  else { mode=2; bx=(bid-192)>>3; }
  int by = bid&7;
  const short* A  = mode==0? QN : mode==1? KG : WVT;
  const short* Bt = mode==0? WQT: mode==1? WKT: VG;

  const int t = threadIdx.x;
  const int w = t>>6, l = t&63;
  const int wr = w>>1, wc = w&1;
  const int fl15 = l&15, fl4 = l>>4;
  const size_t m0 = (size_t)bx*128, n0 = (size_t)by*128;
  const int srow = t>>2, scb = t&3;
  const int sg = scb ^ ((srow>>1)&3);
  const short* Ap = A + (m0+srow)*1024 + 8*sg;
  const short* Bp = Bt + (n0+srow)*1024 + 8*sg;

  f32x4 acc[4][4];
  const f32x4 zero = {0.f,0.f,0.f,0.f};
  #pragma unroll
  for(int m=0;m<4;m++)
    #pragma unroll
    for(int n=0;n<4;n++) acc[m][n] = zero;

  for(int k0=0;k0<1024;k0+=32){
    s16x8 a0 = *(const s16x8*)(Ap + k0);
    s16x8 a1 = *(const s16x8*)(Ap + 64*1024 + k0);
    s16x8 b0 = *(const s16x8*)(Bp + k0);
    s16x8 b1 = *(const s16x8*)(Bp + 64*1024 + k0);
    __syncthreads();
    *(s16x8*)(Ab + srow*32 + scb*8)      = a0;
    *(s16x8*)(Ab + (64+srow)*32 + scb*8) = a1;
    *(s16x8*)(Bb + srow*32 + scb*8)      = b0;
    *(s16x8*)(Bb + (64+srow)*32 + scb*8) = b1;
    __syncthreads();
    s16x8 af[4], bff[4];
    #pragma unroll
    for(int m=0;m<4;m++){
      int row = wr*64 + m*16 + fl15;
      int gg = fl4 ^ ((row>>1)&3);
      af[m] = *(const s16x8*)(Ab + row*32 + gg*8);
    }
    #pragma unroll
    for(int n=0;n<4;n++){
      int row = wc*64 + n*16 + fl15;
      int gg = fl4 ^ ((row>>1)&3);
      bff[n] = *(const s16x8*)(Bb + row*32 + gg*8);
    }
    #pragma unroll
    for(int m=0;m<4;m++)
      #pragma unroll
      for(int n=0;n<4;n++)
        acc[m][n] = MFMA(af[m], bff[n], acc[m][n]);
  }

  #pragma unroll
  for(int m=0;m<4;m++){
    #pragma unroll
    for(int n=0;n<4;n++){
      int mgb = (int)m0 + wr*64 + m*16 + 4*fl4;
      int ng  = (int)n0 + wc*64 + n*16 + fl15;
      #pragma unroll
      for(int p=0;p<4;p++){
        int mg = mgb + p;
        float v = acc[m][n][p];
        if(mode==0){ int b=mg>>10, i=mg&1023, h=ng>>6, d=ng&63;
          QB[((size_t)((b*16+h)*1024+i))*64 + d] = f2b(v); }
        else if(mode==1){ int b=mg>>9, jj=mg&511, h=ng>>6, d=ng&63;
          KB[((size_t)((b*16+h)*512+jj))*64 + d] = f2b(v); }
        else { int h=mg>>6, d=mg&63, b=ng>>9, jj=ng&511;
          VT[((size_t)((b*16+h)*64+d))*512 + jj] = f2b(v); }
      }
    }
  }
}

// ---------- output GEMM ----------
__global__ __launch_bounds__(256) void k_gemmO(
    const short* __restrict__ A, const short* __restrict__ Bt,
    float* __restrict__ out, const float* __restrict__ bo,
    const float* __restrict__ ctxf){
  __shared__ __align__(16) short Ab[128*32];
  __shared__ __align__(16) short Bb[128*32];
  const int t = threadIdx.x;
  const int w = t>>6, l = t&63;
  const int wr = w>>1, wc = w&1;
  const int fl15 = l&15, fl4 = l>>4;
  const size_t m0 = (size_t)blockIdx.x*128, n0 = (size_t)blockIdx.y*128;
  const int srow = t>>2, scb = t&3;
  const int sg = scb ^ ((srow>>1)&3);
  const short* Ap = A + (m0+srow)*1024 + 8*sg;
  const short* Bp = Bt + (n0+srow)*1024 + 8*sg;

  f32x4 acc[4][4];
  const f32x4 zero = {0.f,0.f,0.f,0.f};
  #pragma unroll
  for(int m=0;m<4;m++)
    #pragma unroll
    for(int n=0;n<4;n++) acc[m][n] = zero;

  for(int k0=0;k0<1024;k0+=32){
    s16x8 a0 = *(const s16x8*)(Ap + k0);
    s16x8 a1 = *(const s16x8*)(Ap + 64*1024 + k0);
    s16x8 b0 = *(const s16x8*)(Bp + k0);
    s16x8 b1 = *(const s16x8*)(Bp + 64*1024 + k0);
    __syncthreads();
    *(s16x8*)(Ab + srow*32 + scb*8)      = a0;
    *(s16x8*)(Ab + (64+srow)*32 + scb*8) = a1;
    *(s16x8*)(Bb + srow*32 + scb*8)      = b0;
    *(s16x8*)(Bb + (64+srow)*32 + scb*8) = b1;
    __syncthreads();
    s16x8 af[4], bff[4];
    #pragma unroll
    for(int m=0;m<4;m++){
      int row = wr*64 + m*16 + fl15;
      int gg = fl4 ^ ((row>>1)&3);
      af[m] = *(const s16x8*)(Ab + row*32 + gg*8);
    }
    #pragma unroll
    for(int n=0;n<4;n++){
      int row = wc*64 + n*16 + fl15;
      int gg = fl4 ^ ((row>>1)&3);
      bff[n] = *(const s16x8*)(Bb + row*32 + gg*8);
    }
    #pragma unroll
    for(int m=0;m<4;m++)
      #pragma unroll
      for(int n=0;n<4;n++)
        acc[m][n] = MFMA(af[m], bff[n], acc[m][n]);
  }

  #pragma unroll
  for(int m=0;m<4;m++){
    #pragma unroll
    for(int n=0;n<4;n++){
      int mgb = (int)m0 + wr*64 + m*16 + 4*fl4;
      int ng  = (int)n0 + wc*64 + n*16 + fl15;
      #pragma unroll
      for(int p=0;p<4;p++){
        int mg = mgb + p;
        size_t idx = (size_t)mg*1024 + ng;
        out[idx] = acc[m][n][p] + bo[ng] + ctxf[idx];
      }
    }
  }
}

// ---------- fused rel + flash attention ----------
// Block = (bh, 16-query group). Phase 1: 4 waves build the skewed G window
// (value (r,x) at Gs[chunk][x-xc+r][r], row stride 20 shorts = 40B -> 8B-aligned
// b64 gathers). Phase 2: wave w = keys [128w,128w+128) flash with rel read from
// block-shared Gs. Phase 3: split-K softmax merge in LDS (ps MUST be fl15-reduced).
#define RGS 20
#define GROWS 287
__global__ __launch_bounds__(256,2) void k_attn(const short* __restrict__ qb,
    const short* __restrict__ kb, const short* __restrict__ vt,
    const short* __restrict__ lbf, const int* __restrict__ vf,
    const unsigned int* __restrict__ MB,
    unsigned short* __restrict__ ctxb, float* __restrict__ ctxf){
  __shared__ __align__(16) short Gs[4][GROWS*RGS];   // 45,920 B (reused for merge)
  __shared__ __align__(16) short PB[4][1024];        // 8 KiB
  __shared__ int vfs[512];
  const int t=threadIdx.x, w=t>>6, l=t&63, fl15=l&15, fl4=l>>4;
  const int bh = blockIdx.y;      // 0..31
  const int qg = blockIdx.x;      // 0..63
  const int qw = qg*16;
  for(int i=t;i<512;i+=256) vfs[i]=vf[i];
  __syncthreads();
  const int vf0 = vfs[0];
  const int x0  = 1008 + vf0 - qw;            // >= 0
  const int xcw = x0 + w*256;

  // q fragments (16 rows, shared by all waves)
  const short* qp = qb + ((size_t)(bh*1024 + qw + fl15))*64 + 8*fl4;
  s16x8 qa0 = *(const s16x8*)qp;
  s16x8 qa1 = *(const s16x8*)(qp+32);

  // ---- phase 1: G chunk (wave-private writes) ----
  short* Gw = &Gs[w][0];
  const f32x4 zero = {0.f,0.f,0.f,0.f};
  #pragma unroll 4
  for(int tt=0;tt<17;tt++){
    int xr = xcw + tt*16 + fl15; if(xr>2046) xr = 2046;
    const short* lp = lbf + (size_t)xr*64 + 8*fl4;
    s16x8 b0 = *(const s16x8*)lp;
    s16x8 b1 = *(const s16x8*)(lp+32);
    f32x4 a = zero;
    a = MFMA(qa0,b0,a); a = MFMA(qa1,b1,a);
    int cb = tt*16 + fl15 + 4*fl4;
    #pragma unroll
    for(int p=0;p<4;p++) Gw[(cb+p)*RGS + 4*fl4 + p] = (short)f2b(a[p]);
  }

  // mask bits for rows qw+4*fl4+p, all 32 key-tiles
  const int rowgrp = bh*256 + qg*4 + fl4;
  uint4 mv = ((const uint4*)MB)[rowgrp*16 + fl15];
  unsigned int mbits[4] = {mv.x, mv.y, mv.z, mv.w};

  __syncthreads();   // G ready for cross-wave reads

  // ---- phase 2: flash over this wave's 128 keys (tiles 8w .. 8w+7) ----
  const short* kp_row = kb + ((size_t)(bh*512 + fl15))*64 + 8*fl4;
  const short* vpb[4];
  #pragma unroll
  for(int dt=0;dt<4;dt++)
    vpb[dt] = vt + ((size_t)(bh*64 + dt*16 + fl15))*512 + w*128 + 8*fl4;

  f32x4 facc[4];
  #pragma unroll
  for(int dt=0;dt<4;dt++) facc[dt] = zero;
  float m_run[4] = {-1e30f,-1e30f,-1e30f,-1e30f};
  float ps[4]    = {0.f,0.f,0.f,0.f};
  short* Pw = &PB[w][0];

  for(int c=0;c<2;c++){
    // V fragments for this 64-key chunk
    s16x8 vfr[8];
    #pragma unroll
    for(int dt=0;dt<4;dt++){
      vfr[2*dt]   = *(const s16x8*)(vpb[dt] + c*64);
      vfr[2*dt+1] = *(const s16x8*)(vpb[dt] + c*64 + 32);
    }
    // QK^T + rel + mask
    f32x4 S[4];
    #pragma unroll
    for(int tl=0;tl<4;tl++){
      int ttg = 8*w + 4*c + tl;
      const short* ka = kp_row + (size_t)ttg*1024;
      s16x8 k0v = *(const s16x8*)ka;
      s16x8 k1v = *(const s16x8*)(ka+32);
      f32x4 a = zero;
      a = MFMA(qa0,k0v,a); a = MFMA(qa1,k1v,a);
      int jj = ttg*16 + fl15;
      int o  = vfs[jj] - vf0;                      // 0..1023
      s16x4 rl = *(const s16x4*)(&Gs[o>>8][((o&255)+15)*RGS + 4*fl4]);
      #pragma unroll
      for(int p=0;p<4;p++){
        float sv = (a[p] + b2f((unsigned short)rl[p])) * 0.125f;
        bool mskb = (mbits[p]>>ttg)&1u;
        a[p] = mskb ? -1e30f : sv;
      }
      S[tl] = a;
    }
    // chunk max per row, rescale
    float cm[4];
    #pragma unroll
    for(int p=0;p<4;p++){
      cm[p] = fmaxf(fmaxf(S[0][p],S[1][p]), fmaxf(S[2][p],S[3][p]));
      #pragma unroll
      for(int o=1;o<16;o<<=1) cm[p] = fmaxf(cm[p], __shfl_xor(cm[p],o));
      float mn = fmaxf(m_run[p], cm[p]);
      float fac = __expf(m_run[p]-mn);
      m_run[p] = mn;
      ps[p] *= fac;
      #pragma unroll
      for(int dt=0;dt<4;dt++) facc[dt][p] *= fac;
    }
    // exp + P chunk to wave-private swizzled LDS
    #pragma unroll
    for(int tl=0;tl<4;tl++){
      #pragma unroll
      for(int p=0;p<4;p++){
        float e = __expf(S[tl][p]-m_run[p]);
        ps[p] += e;
        int row = 4*fl4+p;
        Pw[row*64 + ((tl*16 + fl15) ^ (fl4<<4))] = (short)f2b(e);
      }
    }
    // PV accumulate
    #pragma unroll
    for(int s=0;s<2;s++){
      s16x8 pa = *(const s16x8*)(Pw + fl15*64 + ((s*32 + fl4*8) ^ ((fl15>>2)<<4)));
      #pragma unroll
      for(int dt=0;dt<4;dt++)
        facc[dt] = MFMA(pa, vfr[2*dt+s], facc[dt]);
    }
  }

  // reduce ps across the 16 fl15 lanes (per-lane partial sums -> row sums)
  #pragma unroll
  for(int p=0;p<4;p++){
    #pragma unroll
    for(int o=1;o<16;o<<=1) ps[p] += __shfl_xor(ps[p],o);
  }

  // ---- phase 3: split-K merge across the 4 waves (reuse Gs as float buffer) ----
  __syncthreads();                         // all Gs reads done
  float* MT = (float*)&Gs[0][0];           // [4][16] running max
  float* ST = MT + 64;                     // [4][16] running sum
  float* MG = ST + 64;                     // [4][16][65] scaled partial ctx
  if(fl15==0){
    #pragma unroll
    for(int p=0;p<4;p++){ MT[w*16 + 4*fl4+p] = m_run[p]; ST[w*16 + 4*fl4+p] = ps[p]; }
  }
  __syncthreads();
  float scale[4];
  #pragma unroll
  for(int p=0;p<4;p++){
    int row = 4*fl4+p;
    float ms  = fmaxf(fmaxf(MT[row],MT[16+row]), fmaxf(MT[32+row],MT[48+row]));
    float den = __expf(MT[row]-ms)*ST[row] + __expf(MT[16+row]-ms)*ST[16+row]
              + __expf(MT[32+row]-ms)*ST[32+row] + __expf(MT[48+row]-ms)*ST[48+row];
    scale[p] = __expf(m_run[p]-ms) / den;
  }
  #pragma unroll
  for(int dt=0;dt<4;dt++)
    #pragma unroll
    for(int p=0;p<4;p++)
      MG[(w*16 + 4*fl4+p)*65 + dt*16 + fl15] = facc[dt][p]*scale[p];
  __syncthreads();
  // wave w stores the d-slice dt = w
  const int b = bh>>4, h = bh&15;
  #pragma unroll
  for(int p=0;p<4;p++){
    int row = 4*fl4+p;
    float v = MG[(row)*65    + w*16+fl15] + MG[(16+row)*65 + w*16+fl15]
            + MG[(32+row)*65 + w*16+fl15] + MG[(48+row)*65 + w*16+fl15];
    size_t idx = ((size_t)(b*1024 + qw + row))*1024 + h*64 + w*16 + fl15;
    ctxb[idx] = f2b(v);
    ctxf[idx] = v;
  }
}

// ---------- launch ----------
extern "C" void kernel_launch(void* const* d_in, const int* in_sizes, int n_in,
                              void* d_out, int out_size, void* d_ws, size_t ws_size,
                              hipStream_t stream){
  (void)in_sizes; (void)n_in; (void)out_size; (void)ws_size;
  const float* Q  = (const float*)d_in[0];
  const float* K  = (const float*)d_in[1];
  const float* V  = (const float*)d_in[2];
  const float* Lt = (const float*)d_in[3];
  const int*   vf = (const int*)d_in[4];
  const void*  mk = d_in[5];
  const float* Wq = (const float*)d_in[6];
  const float* Wk = (const float*)d_in[7];
  const float* Wv = (const float*)d_in[8];
  const float* Wo = (const float*)d_in[9];
  const float* bo = (const float*)d_in[10];
  const float* lg = (const float*)d_in[11];
  const float* lb = (const float*)d_in[12];

  char* base = (char*)d_ws;
  size_t off = 0;
  auto alloc = [&](size_t bytes)->char*{
    char* p = base + off; off += (bytes + 255) & ~(size_t)255; return p; };
  unsigned int*   MBp = (unsigned int*)alloc(32768ull*16*4);
  unsigned short* QN  = (unsigned short*)alloc(2048ull*1024*2);
  unsigned short* KG  = (unsigned short*)alloc(1024ull*1024*2);
  unsigned short* VG  = (unsigned short*)alloc(1024ull*1024*2);
  unsigned short* WQT = (unsigned short*)alloc(1024ull*1024*2);
  unsigned short* WKT = (unsigned short*)alloc(1024ull*1024*2);
  unsigned short* WVT = (unsigned short*)alloc(1024ull*1024*2);
  unsigned short* WOT = (unsigned short*)alloc(1024ull*1024*2);
  unsigned short* LB  = (unsigned short*)alloc(2047ull*64*2);
  unsigned short* QB  = (unsigned short*)alloc(32ull*1024*64*2);
  unsigned short* KB  = (unsigned short*)alloc(32ull*512*64*2);
  unsigned short* VT  = (unsigned short*)alloc(32ull*64*512*2);
  unsigned short* CB  = (unsigned short*)alloc(2048ull*1024*2);
  float*          CF  = (float*)alloc(2048ull*1024*4);

  k_mask<<<2048,256,0,stream>>>((const unsigned char*)mk, MBp);
  k_prep<<<5632,256,0,stream>>>(Q, lg, lb, QN, K, V, vf, KG, VG, Lt, LB,
                                Wq, Wk, Wv, Wo, WQT, WKT, WVT, WOT);
  k_proj<<<256,256,0,stream>>>((const short*)QN,(const short*)WQT,
                               (const short*)KG,(const short*)WKT,
                               (const short*)WVT,(const short*)VG,
                               QB, KB, VT);
  k_attn<<<dim3(64,32),256,0,stream>>>((const short*)QB,(const short*)KB,(const short*)VT,
                                       (const short*)LB, vf, MBp, CB, CF);
  k_gemmO<<<dim3(16,8),256,0,stream>>>((const short*)CB,(const short*)WOT,
                                       (float*)d_out, bo, CF);
}

// Round 8
// 144.094 us; speedup vs baseline: 1.8814x; 1.0131x over previous
//
#include <hip/hip_runtime.h>
#include <stdint.h>
#include <stddef.h>

// ---------- types ----------
typedef __attribute__((ext_vector_type(8))) short s16x8;
typedef __attribute__((ext_vector_type(4))) short s16x4;
typedef __attribute__((ext_vector_type(4))) float f32x4;

#define MFMA(a,b,c) __builtin_amdgcn_mfma_f32_16x16x32_bf16((a),(b),(c),0,0,0)

static __device__ __forceinline__ unsigned short f2b(float f){
  unsigned int b = __float_as_uint(f);
  b = (b + 0x7FFFu + ((b>>16)&1u)) >> 16;     // RNE
  return (unsigned short)b;
}
static __device__ __forceinline__ float b2f(unsigned short u){
  return __uint_as_float(((unsigned int)u)<<16);
}

// B=2, T1=1024, T2=512, H=16, DH=64, DM=1024, SCALE=0.125

// ---------- mask pre-pack: MB[rowgrp][f][p] words, bit i = mask[row][i*16+f] ----------
__global__ __launch_bounds__(256) void k_mask(const unsigned char* __restrict__ m,
    unsigned int* __restrict__ MB){
  const int t = threadIdx.x;
  const size_t g0 = (size_t)blockIdx.x*16;          // first of 16 global rows (32768 total)
  __shared__ int cnt1, cnt23;
  if(t==0){ cnt1=0; cnt23=0; }
  __syncthreads();
  const uint4* bp = (const uint4*)(m + g0*512);
  int l1=0,l23=0;
  #pragma unroll
  for(int i=0;i<2;i++){
    uint4 v = bp[t + i*256];
    unsigned int ws[4] = {v.x,v.y,v.z,v.w};
    #pragma unroll
    for(int j=0;j<4;j++){
      if((ws[j]>>8)&0xFFu) l1++;
      if(ws[j]>>16)        l23++;
    }
  }
  #pragma unroll
  for(int o=1;o<64;o<<=1){ l1 += __shfl_xor(l1,o); l23 += __shfl_xor(l23,o); }
  if((t&63)==0){ atomicAdd(&cnt1,l1); atomicAdd(&cnt23,l23); }
  __syncthreads();
  const int flag = cnt1 ? 1 : (cnt23 ? 2 : 0);

  const int rl = t>>4, f = t&15;
  const size_t base = (g0 + rl)*512 + f;
  unsigned int word = 0;
  if(flag==0){
    const int* p = (const int*)m;
    #pragma unroll
    for(int i=0;i<32;i++) word |= (p[base+i*16]!=0 ? 1u:0u) << i;
  } else if(flag==1){
    #pragma unroll
    for(int i=0;i<32;i++) word |= (m[base+i*16]!=0 ? 1u:0u) << i;
  } else {
    const float* p = (const float*)m;
    #pragma unroll
    for(int i=0;i<32;i++) word |= (p[base+i*16]!=0.f ? 1u:0u) << i;
  }
  MB[((size_t)blockIdx.x*4 + (t>>6))*64 + f*4 + (rl&3)] = word;
}

// ---------- fused prep: LN(Q), gather K/V, cast L, transpose 4 weights ----------
__global__ __launch_bounds__(256) void k_prep(
    const float* __restrict__ Q, const float* __restrict__ g, const float* __restrict__ be,
    unsigned short* __restrict__ Qn,
    const float* __restrict__ K, const float* __restrict__ V, const int* __restrict__ vf,
    unsigned short* __restrict__ Kg, unsigned short* __restrict__ Vg,
    const float* __restrict__ L, unsigned short* __restrict__ Lb,
    const float* __restrict__ W0, const float* __restrict__ W1,
    const float* __restrict__ W2, const float* __restrict__ W3,
    unsigned short* __restrict__ D0, unsigned short* __restrict__ D1,
    unsigned short* __restrict__ D2, unsigned short* __restrict__ D3){
  __shared__ float tile[64][65];
  __shared__ float red[8];
  const int bid = blockIdx.x, t = threadIdx.x;
  if(bid < 2048){                       // ---- LayerNorm ----
    const float4* xp = (const float4*)(Q + (size_t)bid*1024);
    float4 v = xp[t];
    float s  = v.x+v.y+v.z+v.w;
    float s2 = v.x*v.x+v.y*v.y+v.z*v.z+v.w*v.w;
    #pragma unroll
    for(int o=1;o<64;o<<=1){ s += __shfl_xor(s,o); s2 += __shfl_xor(s2,o); }
    int w = t>>6, l = t&63;
    if(l==0){ red[w]=s; red[4+w]=s2; }
    __syncthreads();
    s  = red[0]+red[1]+red[2]+red[3];
    s2 = red[4]+red[5]+red[6]+red[7];
    float mu = s*(1.f/1024.f);
    float var = s2*(1.f/1024.f) - mu*mu;
    float rs = rsqrtf(var + 1e-5f);
    float4 gv = ((const float4*)g)[t];
    float4 bv = ((const float4*)be)[t];
    ushort4 o4;
    o4.x = f2b((v.x-mu)*rs*gv.x + bv.x);
    o4.y = f2b((v.y-mu)*rs*gv.y + bv.y);
    o4.z = f2b((v.z-mu)*rs*gv.z + bv.z);
    o4.w = f2b((v.w-mu)*rs*gv.w + bv.w);
    ((ushort4*)(Qn + (size_t)bid*1024))[t] = o4;
  } else if(bid < 4096){                // ---- gather K/V ----
    int row = bid - 2048;               // 0..2047
    int isV = row>>10, r = row&1023;
    int b = r>>9, jj = r&511;
    const float* src = (isV? V : K) + ((size_t)(b*1024 + vf[jj]))*1024;
    unsigned short* dst = (isV? Vg : Kg) + (size_t)r*1024;
    float4 v = ((const float4*)src)[t];
    ushort4 o; o.x=f2b(v.x); o.y=f2b(v.y); o.z=f2b(v.z); o.w=f2b(v.w);
    ((ushort4*)dst)[t] = o;
  } else if(bid < 4608){                // ---- cast lookup table ----
    int i = (bid-4096)*256 + t;
    if(i < 2047*64) Lb[i] = f2b(L[i]);
  } else {                              // ---- weight transpose ----
    int idx = bid - 4608;               // 0..1023
    int z = idx>>8, rem = idx&255;
    int k0 = (rem&15)*64, n0 = (rem>>4)*64;
    const float* S = z==0?W0: z==1?W1: z==2?W2:W3;
    unsigned short* D = z==0?D0: z==1?D1: z==2?D2:D3;
    int tr = t>>6, tc = t&63;
    #pragma unroll
    for(int it=0;it<16;it++){ int r = it*4+tr; tile[r][tc] = S[(size_t)(k0+r)*1024 + n0+tc]; }
    __syncthreads();
    #pragma unroll
    for(int it=0;it<16;it++){ int r = it*4+tr; D[(size_t)(n0+r)*1024 + k0+tc] = f2b(tile[tc][r]); }
  }
}

// ---------- merged projection GEMM: 256 blocks, runtime mode ----------
__global__ __launch_bounds__(256) void k_proj(
    const short* __restrict__ QN, const short* __restrict__ WQT,
    const short* __restrict__ KG, const short* __restrict__ WKT,
    const short* __restrict__ WVT, const short* __restrict__ VG,
    unsigned short* __restrict__ QB, unsigned short* __restrict__ KB,
    unsigned short* __restrict__ VT){
  __shared__ __align__(16) short Ab[128*32];
  __shared__ __align__(16) short Bb[128*32];
  int bid = blockIdx.x;
  int mode, bx;
  if(bid<128){ mode=0; bx=bid>>3; }
  else if(bid<192){ mode=1; bx=(bid-128)>>3; }
  else { mode=2; bx=(bid-192)>>3; }
  int by = bid&7;
  const short* A  = mode==0? QN : mode==1? KG : WVT;
  const short* Bt = mode==0? WQT: mode==1? WKT: VG;

  const int t = threadIdx.x;
  const int w = t>>6, l = t&63;
  const int wr = w>>1, wc = w&1;
  const int fl15 = l&15, fl4 = l>>4;
  const size_t m0 = (size_t)bx*128, n0 = (size_t)by*128;
  const int srow = t>>2, scb = t&3;
  const int sg = scb ^ ((srow>>1)&3);
  const short* Ap = A + (m0+srow)*1024 + 8*sg;
  const short* Bp = Bt + (n0+srow)*1024 + 8*sg;

  f32x4 acc[4][4];
  const f32x4 zero = {0.f,0.f,0.f,0.f};
  #pragma unroll
  for(int m=0;m<4;m++)
    #pragma unroll
    for(int n=0;n<4;n++) acc[m][n] = zero;

  for(int k0=0;k0<1024;k0+=32){
    s16x8 a0 = *(const s16x8*)(Ap + k0);
    s16x8 a1 = *(const s16x8*)(Ap + 64*1024 + k0);
    s16x8 b0 = *(const s16x8*)(Bp + k0);
    s16x8 b1 = *(const s16x8*)(Bp + 64*1024 + k0);
    __syncthreads();
    *(s16x8*)(Ab + srow*32 + scb*8)      = a0;
    *(s16x8*)(Ab + (64+srow)*32 + scb*8) = a1;
    *(s16x8*)(Bb + srow*32 + scb*8)      = b0;
    *(s16x8*)(Bb + (64+srow)*32 + scb*8) = b1;
    __syncthreads();
    s16x8 af[4], bff[4];
    #pragma unroll
    for(int m=0;m<4;m++){
      int row = wr*64 + m*16 + fl15;
      int gg = fl4 ^ ((row>>1)&3);
      af[m] = *(const s16x8*)(Ab + row*32 + gg*8);
    }
    #pragma unroll
    for(int n=0;n<4;n++){
      int row = wc*64 + n*16 + fl15;
      int gg = fl4 ^ ((row>>1)&3);
      bff[n] = *(const s16x8*)(Bb + row*32 + gg*8);
    }
    #pragma unroll
    for(int m=0;m<4;m++)
      #pragma unroll
      for(int n=0;n<4;n++)
        acc[m][n] = MFMA(af[m], bff[n], acc[m][n]);
  }

  #pragma unroll
  for(int m=0;m<4;m++){
    #pragma unroll
    for(int n=0;n<4;n++){
      int mgb = (int)m0 + wr*64 + m*16 + 4*fl4;
      int ng  = (int)n0 + wc*64 + n*16 + fl15;
      #pragma unroll
      for(int p=0;p<4;p++){
        int mg = mgb + p;
        float v = acc[m][n][p];
        if(mode==0){ int b=mg>>10, i=mg&1023, h=ng>>6, d=ng&63;
          QB[((size_t)((b*16+h)*1024+i))*64 + d] = f2b(v); }
        else if(mode==1){ int b=mg>>9, jj=mg&511, h=ng>>6, d=ng&63;
          KB[((size_t)((b*16+h)*512+jj))*64 + d] = f2b(v); }
        else { int h=mg>>6, d=mg&63, b=ng>>9, jj=ng&511;
          VT[((size_t)((b*16+h)*64+d))*512 + jj] = f2b(v); }
      }
    }
  }
}

// ---------- output GEMM ----------
__global__ __launch_bounds__(256) void k_gemmO(
    const short* __restrict__ A, const short* __restrict__ Bt,
    float* __restrict__ out, const float* __restrict__ bo,
    const float* __restrict__ ctxf){
  __shared__ __align__(16) short Ab[128*32];
  __shared__ __align__(16) short Bb[128*32];
  const int t = threadIdx.x;
  const int w = t>>6, l = t&63;
  const int wr = w>>1, wc = w&1;
  const int fl15 = l&15, fl4 = l>>4;
  const size_t m0 = (size_t)blockIdx.x*128, n0 = (size_t)blockIdx.y*128;
  const int srow = t>>2, scb = t&3;
  const int sg = scb ^ ((srow>>1)&3);
  const short* Ap = A + (m0+srow)*1024 + 8*sg;
  const short* Bp = Bt + (n0+srow)*1024 + 8*sg;

  f32x4 acc[4][4];
  const f32x4 zero = {0.f,0.f,0.f,0.f};
  #pragma unroll
  for(int m=0;m<4;m++)
    #pragma unroll
    for(int n=0;n<4;n++) acc[m][n] = zero;

  for(int k0=0;k0<1024;k0+=32){
    s16x8 a0 = *(const s16x8*)(Ap + k0);
    s16x8 a1 = *(const s16x8*)(Ap + 64*1024 + k0);
    s16x8 b0 = *(const s16x8*)(Bp + k0);
    s16x8 b1 = *(const s16x8*)(Bp + 64*1024 + k0);
    __syncthreads();
    *(s16x8*)(Ab + srow*32 + scb*8)      = a0;
    *(s16x8*)(Ab + (64+srow)*32 + scb*8) = a1;
    *(s16x8*)(Bb + srow*32 + scb*8)      = b0;
    *(s16x8*)(Bb + (64+srow)*32 + scb*8) = b1;
    __syncthreads();
    s16x8 af[4], bff[4];
    #pragma unroll
    for(int m=0;m<4;m++){
      int row = wr*64 + m*16 + fl15;
      int gg = fl4 ^ ((row>>1)&3);
      af[m] = *(const s16x8*)(Ab + row*32 + gg*8);
    }
    #pragma unroll
    for(int n=0;n<4;n++){
      int row = wc*64 + n*16 + fl15;
      int gg = fl4 ^ ((row>>1)&3);
      bff[n] = *(const s16x8*)(Bb + row*32 + gg*8);
    }
    #pragma unroll
    for(int m=0;m<4;m++)
      #pragma unroll
      for(int n=0;n<4;n++)
        acc[m][n] = MFMA(af[m], bff[n], acc[m][n]);
  }

  #pragma unroll
  for(int m=0;m<4;m++){
    #pragma unroll
    for(int n=0;n<4;n++){
      int mgb = (int)m0 + wr*64 + m*16 + 4*fl4;
      int ng  = (int)n0 + wc*64 + n*16 + fl15;
      #pragma unroll
      for(int p=0;p<4;p++){
        int mg = mgb + p;
        size_t idx = (size_t)mg*1024 + ng;
        out[idx] = acc[m][n][p] + bo[ng] + ctxf[idx];
      }
    }
  }
}

// ---------- fused rel + flash attention (deep register prefetch) ----------
// Block = (bh, 16-query group). All global loads (K 8 tiles, V both chunks' first,
// q, mask) issued BEFORE phase-1 G compute so L2/HBM latency hides under MFMA.
// Phase 1: 4 waves build skewed G window (value (r,x) at Gs[chunk][x-xc+r][r]).
// Phase 2: wave w = keys [128w,128w+128), pure register flash.
// Phase 3: split-K merge (ps fl15-reduced first).
#define RGS 20
#define GROWS 287
__global__ __launch_bounds__(256,2) void k_attn(const short* __restrict__ qb,
    const short* __restrict__ kb, const short* __restrict__ vt,
    const short* __restrict__ lbf, const int* __restrict__ vf,
    const unsigned int* __restrict__ MB,
    unsigned short* __restrict__ ctxb, float* __restrict__ ctxf){
  __shared__ __align__(16) short Gs[4][GROWS*RGS];   // 45,920 B (reused for merge)
  __shared__ __align__(16) short PB[4][1024];        // 8 KiB
  __shared__ int vfs[512];
  const int t=threadIdx.x, w=t>>6, l=t&63, fl15=l&15, fl4=l>>4;
  const int bh = blockIdx.y;      // 0..31
  const int qg = blockIdx.x;      // 0..63
  const int qw = qg*16;

  // ======== issue ALL independent global loads up front ========
  const short* qp = qb + ((size_t)(bh*1024 + qw + fl15))*64 + 8*fl4;
  s16x8 qa0 = *(const s16x8*)qp;
  s16x8 qa1 = *(const s16x8*)(qp+32);

  const int rowgrp = bh*256 + qg*4 + fl4;
  uint4 mv = ((const uint4*)MB)[rowgrp*16 + fl15];

  // K fragments for this wave's 8 key-tiles
  const short* kp_row = kb + ((size_t)(bh*512 + fl15))*64 + 8*fl4;
  s16x8 kf[16];
  #pragma unroll
  for(int i=0;i<8;i++){
    const short* ka = kp_row + (size_t)(8*w+i)*1024;
    kf[2*i]   = *(const s16x8*)ka;
    kf[2*i+1] = *(const s16x8*)(ka+32);
  }
  // V fragments, chunk 0
  const short* vpb[4];
  #pragma unroll
  for(int dt=0;dt<4;dt++)
    vpb[dt] = vt + ((size_t)(bh*64 + dt*16 + fl15))*512 + w*128 + 8*fl4;
  s16x8 vfr0[8];
  #pragma unroll
  for(int dt=0;dt<4;dt++){
    vfr0[2*dt]   = *(const s16x8*)(vpb[dt]);
    vfr0[2*dt+1] = *(const s16x8*)(vpb[dt] + 32);
  }

  for(int i=t;i<512;i+=256) vfs[i]=vf[i];
  __syncthreads();
  const int vf0 = vfs[0];
  const int x0  = 1008 + vf0 - qw;            // >= 0
  const int xcw = x0 + w*256;

  // ---- phase 1: G chunk (wave-private writes) ----
  short* Gw = &Gs[w][0];
  const f32x4 zero = {0.f,0.f,0.f,0.f};
  #pragma unroll 4
  for(int tt=0;tt<17;tt++){
    int xr = xcw + tt*16 + fl15; if(xr>2046) xr = 2046;
    const short* lp = lbf + (size_t)xr*64 + 8*fl4;
    s16x8 b0 = *(const s16x8*)lp;
    s16x8 b1 = *(const s16x8*)(lp+32);
    f32x4 a = zero;
    a = MFMA(qa0,b0,a); a = MFMA(qa1,b1,a);
    int cb = tt*16 + fl15 + 4*fl4;
    #pragma unroll
    for(int p=0;p<4;p++) Gw[(cb+p)*RGS + 4*fl4 + p] = (short)f2b(a[p]);
  }

  unsigned int mbits[4] = {mv.x, mv.y, mv.z, mv.w};
  __syncthreads();   // G ready for cross-wave reads

  // ---- phase 2: flash over this wave's 128 keys (tiles 8w .. 8w+7) ----
  // rel gathers for all 8 tiles, issued as a batch (LDS latency overlaps QK MFMAs)
  s16x4 rl[8];
  #pragma unroll
  for(int i=0;i<8;i++){
    int jj = (8*w+i)*16 + fl15;
    int o  = vfs[jj] - vf0;                      // 0..1023
    rl[i] = *(const s16x4*)(&Gs[o>>8][((o&255)+15)*RGS + 4*fl4]);
  }

  f32x4 facc[4];
  #pragma unroll
  for(int dt=0;dt<4;dt++) facc[dt] = zero;
  float m_run[4] = {-1e30f,-1e30f,-1e30f,-1e30f};
  float ps[4]    = {0.f,0.f,0.f,0.f};
  short* Pw = &PB[w][0];

  // V fragments, chunk 1 (issue before chunk-0 compute; completes during it)
  s16x8 vfr1[8];
  #pragma unroll
  for(int dt=0;dt<4;dt++){
    vfr1[2*dt]   = *(const s16x8*)(vpb[dt] + 64);
    vfr1[2*dt+1] = *(const s16x8*)(vpb[dt] + 64 + 32);
  }

  #pragma unroll
  for(int c=0;c<2;c++){
    // QK^T + rel + mask
    f32x4 S[4];
    #pragma unroll
    for(int tl=0;tl<4;tl++){
      int i = 4*c + tl;
      int ttg = 8*w + i;
      f32x4 a = zero;
      a = MFMA(qa0, kf[2*i], a); a = MFMA(qa1, kf[2*i+1], a);
      #pragma unroll
      for(int p=0;p<4;p++){
        float sv = (a[p] + b2f((unsigned short)rl[i][p])) * 0.125f;
        bool mskb = (mbits[p]>>ttg)&1u;
        a[p] = mskb ? -1e30f : sv;
      }
      S[tl] = a;
    }
    // chunk max per row, rescale
    float cm[4];
    #pragma unroll
    for(int p=0;p<4;p++){
      cm[p] = fmaxf(fmaxf(S[0][p],S[1][p]), fmaxf(S[2][p],S[3][p]));
      #pragma unroll
      for(int o=1;o<16;o<<=1) cm[p] = fmaxf(cm[p], __shfl_xor(cm[p],o));
      float mn = fmaxf(m_run[p], cm[p]);
      float fac = __expf(m_run[p]-mn);
      m_run[p] = mn;
      ps[p] *= fac;
      #pragma unroll
      for(int dt=0;dt<4;dt++) facc[dt][p] *= fac;
    }
    // exp + P chunk to wave-private swizzled LDS
    #pragma unroll
    for(int tl=0;tl<4;tl++){
      #pragma unroll
      for(int p=0;p<4;p++){
        float e = __expf(S[tl][p]-m_run[p]);
        ps[p] += e;
        int row = 4*fl4+p;
        Pw[row*64 + ((tl*16 + fl15) ^ (fl4<<4))] = (short)f2b(e);
      }
    }
    // PV accumulate
    #pragma unroll
    for(int s=0;s<2;s++){
      s16x8 pa = *(const s16x8*)(Pw + fl15*64 + ((s*32 + fl4*8) ^ ((fl15>>2)<<4)));
      #pragma unroll
      for(int dt=0;dt<4;dt++)
        facc[dt] = MFMA(pa, (c==0? vfr0 : vfr1)[2*dt+s], facc[dt]);
    }
  }

  // reduce ps across the 16 fl15 lanes (per-lane partial sums -> row sums)
  #pragma unroll
  for(int p=0;p<4;p++){
    #pragma unroll
    for(int o=1;o<16;o<<=1) ps[p] += __shfl_xor(ps[p],o);
  }

  // ---- phase 3: split-K merge across the 4 waves (reuse Gs as float buffer) ----
  __syncthreads();                         // all Gs reads done
  float* MT = (float*)&Gs[0][0];           // [4][16] running max
  float* ST = MT + 64;                     // [4][16] running sum
  float* MG = ST + 64;                     // [4][16][65] scaled partial ctx
  if(fl15==0){
    #pragma unroll
    for(int p=0;p<4;p++){ MT[w*16 + 4*fl4+p] = m_run[p]; ST[w*16 + 4*fl4+p] = ps[p]; }
  }
  __syncthreads();
  float scale[4];
  #pragma unroll
  for(int p=0;p<4;p++){
    int row = 4*fl4+p;
    float ms  = fmaxf(fmaxf(MT[row],MT[16+row]), fmaxf(MT[32+row],MT[48+row]));
    float den = __expf(MT[row]-ms)*ST[row] + __expf(MT[16+row]-ms)*ST[16+row]
              + __expf(MT[32+row]-ms)*ST[32+row] + __expf(MT[48+row]-ms)*ST[48+row];
    scale[p] = __expf(m_run[p]-ms) / den;
  }
  #pragma unroll
  for(int dt=0;dt<4;dt++)
    #pragma unroll
    for(int p=0;p<4;p++)
      MG[(w*16 + 4*fl4+p)*65 + dt*16 + fl15] = facc[dt][p]*scale[p];
  __syncthreads();
  // wave w stores the d-slice dt = w
  const int b = bh>>4, h = bh&15;
  #pragma unroll
  for(int p=0;p<4;p++){
    int row = 4*fl4+p;
    float v = MG[(row)*65    + w*16+fl15] + MG[(16+row)*65 + w*16+fl15]
            + MG[(32+row)*65 + w*16+fl15] + MG[(48+row)*65 + w*16+fl15];
    size_t idx = ((size_t)(b*1024 + qw + row))*1024 + h*64 + w*16 + fl15;
    ctxb[idx] = f2b(v);
    ctxf[idx] = v;
  }
}

// ---------- launch ----------
extern "C" void kernel_launch(void* const* d_in, const int* in_sizes, int n_in,
                              void* d_out, int out_size, void* d_ws, size_t ws_size,
                              hipStream_t stream){
  (void)in_sizes; (void)n_in; (void)out_size; (void)ws_size;
  const float* Q  = (const float*)d_in[0];
  const float* K  = (const float*)d_in[1];
  const float* V  = (const float*)d_in[2];
  const float* Lt = (const float*)d_in[3];
  const int*   vf = (const int*)d_in[4];
  const void*  mk = d_in[5];
  const float* Wq = (const float*)d_in[6];
  const float* Wk = (const float*)d_in[7];
  const float* Wv = (const float*)d_in[8];
  const float* Wo = (const float*)d_in[9];
  const float* bo = (const float*)d_in[10];
  const float* lg = (const float*)d_in[11];
  const float* lb = (const float*)d_in[12];

  char* base = (char*)d_ws;
  size_t off = 0;
  auto alloc = [&](size_t bytes)->char*{
    char* p = base + off; off += (bytes + 255) & ~(size_t)255; return p; };
  unsigned int*   MBp = (unsigned int*)alloc(32768ull*16*4);
  unsigned short* QN  = (unsigned short*)alloc(2048ull*1024*2);
  unsigned short* KG  = (unsigned short*)alloc(1024ull*1024*2);
  unsigned short* VG  = (unsigned short*)alloc(1024ull*1024*2);
  unsigned short* WQT = (unsigned short*)alloc(1024ull*1024*2);
  unsigned short* WKT = (unsigned short*)alloc(1024ull*1024*2);
  unsigned short* WVT = (unsigned short*)alloc(1024ull*1024*2);
  unsigned short* WOT = (unsigned short*)alloc(1024ull*1024*2);
  unsigned short* LB  = (unsigned short*)alloc(2047ull*64*2);
  unsigned short* QB  = (unsigned short*)alloc(32ull*1024*64*2);
  unsigned short* KB  = (unsigned short*)alloc(32ull*512*64*2);
  unsigned short* VT  = (unsigned short*)alloc(32ull*64*512*2);
  unsigned short* CB  = (unsigned short*)alloc(2048ull*1024*2);
  float*          CF  = (float*)alloc(2048ull*1024*4);

  k_mask<<<2048,256,0,stream>>>((const unsigned char*)mk, MBp);
  k_prep<<<5632,256,0,stream>>>(Q, lg, lb, QN, K, V, vf, KG, VG, Lt, LB,
                                Wq, Wk, Wv, Wo, WQT, WKT, WVT, WOT);
  k_proj<<<256,256,0,stream>>>((const short*)QN,(const short*)WQT,
                               (const short*)KG,(const short*)WKT,
                               (const short*)WVT,(const short*)VG,
                               QB, KB, VT);
  k_attn<<<dim3(64,32),256,0,stream>>>((const short*)QB,(const short*)KB,(const short*)VT,
                                       (const short*)LB, vf, MBp, CB, CF);
  k_gemmO<<<dim3(16,8),256,0,stream>>>((const short*)CB,(const short*)WOT,
                                       (float*)d_out, bo, CF);
}